// Round 1
// baseline (2769.243 us; speedup 1.0000x reference)
//
#include <hip/hip_runtime.h>
#include <hip/hip_bf16.h>
#include <math.h>

#define TT   4096   // tokens
#define DM   512    // model dim
#define NE   64     // routed experts
#define TOPK 2
#define HE   256    // expert hidden
#define HSH  2048   // shared expert hidden

__device__ __forceinline__ float sig_(float z){ return 1.f/(1.f+__expf(-z)); }

// ---------------------------------------------------------------------------
// Kernel 1: per-token LayerNorm stats + nx, gate logits + top-2 selection.
// One block (256 thr) per token.
// ---------------------------------------------------------------------------
__global__ __launch_bounds__(256) void k_ln_gate(
    const float* __restrict__ x, const float* __restrict__ Wg, const float* __restrict__ bg,
    float* __restrict__ nx, int* __restrict__ top_idx, float* __restrict__ top_w)
{
  __shared__ float xs[DM];
  __shared__ float sred[4], ssred[4];
  __shared__ float sc[NE];
  const int tid = threadIdx.x;
  const int t   = blockIdx.x;

  float2 v = reinterpret_cast<const float2*>(x + (size_t)t*DM)[tid];
  xs[2*tid]   = v.x;
  xs[2*tid+1] = v.y;
  float s  = v.x + v.y;
  float ss = v.x*v.x + v.y*v.y;
  #pragma unroll
  for (int o = 32; o > 0; o >>= 1){ s += __shfl_xor(s, o); ss += __shfl_xor(ss, o); }
  const int wid = tid >> 6, lane = tid & 63;
  if (lane == 0){ sred[wid] = s; ssred[wid] = ss; }
  __syncthreads();
  const float tot = sred[0]+sred[1]+sred[2]+sred[3];
  const float tss = ssred[0]+ssred[1]+ssred[2]+ssred[3];
  const float mu  = tot * (1.f/DM);
  const float var = tss * (1.f/DM) - mu*mu;
  const float rstd = rsqrtf(var + 1e-5f);
  float2 nv; nv.x = (v.x-mu)*rstd; nv.y = (v.y-mu)*rstd;
  reinterpret_cast<float2*>(nx + (size_t)t*DM)[tid] = nv;

  // gate logits: 4 threads per expert
  const int e = tid >> 2, sub = tid & 3;
  const float* wrow = Wg + (size_t)e*DM;
  float acc = 0.f;
  for (int d = sub; d < DM; d += 4) acc += xs[d]*wrow[d];
  acc += __shfl_xor(acc, 1);
  acc += __shfl_xor(acc, 2);
  if (sub == 0) sc[e] = acc + bg[e];
  __syncthreads();

  // top-2 on wave 0 (logits; monotonic with sigmoid so selection matches ref)
  if (tid < 64) {
    const float s0 = sc[tid];
    float m = s0; int mi = tid;
    #pragma unroll
    for (int o = 1; o < 64; o <<= 1){
      float om = __shfl_xor(m, o); int oi = __shfl_xor(mi, o);
      if (om > m || (om == m && oi < mi)) { m = om; mi = oi; }
    }
    float s1 = (tid == mi) ? -INFINITY : s0;
    float m2 = s1; int mi2 = tid;
    #pragma unroll
    for (int o = 1; o < 64; o <<= 1){
      float om = __shfl_xor(m2, o); int oi = __shfl_xor(mi2, o);
      if (om > m2 || (om == m2 && oi < mi2)) { m2 = om; mi2 = oi; }
    }
    if (tid == 0){
      const float w0 = sig_(m), w1 = sig_(m2);
      const float inv = 1.f/(w0+w1);
      top_idx[2*t]   = mi;
      top_idx[2*t+1] = mi2;
      top_w[2*t]     = w0*inv;
      top_w[2*t+1]   = w1*inv;
    }
  }
}

// ---------------------------------------------------------------------------
// Kernel 2: routing — per-expert counts, exclusive scan, scatter to buckets.
// Single block.
// ---------------------------------------------------------------------------
__global__ __launch_bounds__(256) void k_route(
    const int* __restrict__ top_idx, const float* __restrict__ top_w,
    int* __restrict__ offs, int* __restrict__ bucket_tok, float* __restrict__ bucket_w)
{
  __shared__ int cnt[NE], base_[NE];
  const int tid = threadIdx.x;
  if (tid < NE) cnt[tid] = 0;
  __syncthreads();
  for (int p = tid; p < TT*TOPK; p += 256) atomicAdd(&cnt[top_idx[p]], 1);
  __syncthreads();
  if (tid == 0){
    int run = 0;
    for (int e = 0; e < NE; e++){ base_[e] = run; run += cnt[e]; }
  }
  __syncthreads();
  if (tid < NE) offs[tid] = base_[tid];
  if (tid == 0) offs[NE] = TT*TOPK;
  if (tid < NE) cnt[tid] = 0;
  __syncthreads();
  for (int p = tid; p < TT*TOPK; p += 256){
    const int e = top_idx[p];
    const int pos = base_[e] + atomicAdd(&cnt[e], 1);
    bucket_tok[pos] = p >> 1;
    bucket_w[pos]   = top_w[p];
  }
}

// ---------------------------------------------------------------------------
// Kernel 3: shared expert up-proj: hbuf = silu(nxs@Ws1+bs1)*(nxs@Ws3+bs3)
// grid (T/32, HS/256); each thread owns one h-column, 32 token accumulators.
// ---------------------------------------------------------------------------
__global__ __launch_bounds__(256) void k_shared_h(
    const float* __restrict__ nx, const float* __restrict__ gs, const float* __restrict__ bs,
    const float* __restrict__ Ws1, const float* __restrict__ bs1,
    const float* __restrict__ Ws3, const float* __restrict__ bs3,
    float* __restrict__ hbuf)
{
  __shared__ float xs[32][DM];   // 64 KiB
  const int tid  = threadIdx.x;
  const int t0   = blockIdx.x * 32;
  const int hcol = blockIdx.y * 256 + tid;

  for (int i = tid; i < 32*(DM/4); i += 256){
    const int m = i >> 7, d4 = i & 127;
    float4 v = reinterpret_cast<const float4*>(nx + (size_t)(t0+m)*DM)[d4];
    const float4 g = reinterpret_cast<const float4*>(gs)[d4];
    const float4 b = reinterpret_cast<const float4*>(bs)[d4];
    v.x = v.x*g.x + b.x; v.y = v.y*g.y + b.y; v.z = v.z*g.z + b.z; v.w = v.w*g.w + b.w;
    reinterpret_cast<float4*>(&xs[m][0])[d4] = v;
  }
  __syncthreads();

  float acc1[32], acc3[32];
  #pragma unroll
  for (int m = 0; m < 32; m++){ acc1[m] = 0.f; acc3[m] = 0.f; }

  for (int d4 = 0; d4 < DM/4; d4++){
    const int d = d4*4;
    const float a0 = Ws1[(size_t)(d+0)*HSH + hcol];
    const float a1 = Ws1[(size_t)(d+1)*HSH + hcol];
    const float a2 = Ws1[(size_t)(d+2)*HSH + hcol];
    const float a3 = Ws1[(size_t)(d+3)*HSH + hcol];
    const float c0 = Ws3[(size_t)(d+0)*HSH + hcol];
    const float c1 = Ws3[(size_t)(d+1)*HSH + hcol];
    const float c2 = Ws3[(size_t)(d+2)*HSH + hcol];
    const float c3 = Ws3[(size_t)(d+3)*HSH + hcol];
    #pragma unroll
    for (int m = 0; m < 32; m++){
      const float4 xv = reinterpret_cast<const float4*>(&xs[m][0])[d4];
      acc1[m] += xv.x*a0 + xv.y*a1 + xv.z*a2 + xv.w*a3;
      acc3[m] += xv.x*c0 + xv.y*c1 + xv.z*c2 + xv.w*c3;
    }
  }
  const float b1v = bs1[hcol], b3v = bs3[hcol];
  #pragma unroll
  for (int m = 0; m < 32; m++){
    const float h1 = acc1[m] + b1v;
    const float h3 = acc3[m] + b3v;
    hbuf[(size_t)(t0+m)*HSH + hcol] = h1 * sig_(h1) * h3;
  }
}

// ---------------------------------------------------------------------------
// Kernel 4: shared expert down-proj: out += hbuf@Ws2 (+bs2 from the cb==0 half)
// grid (T/32, 2); each block handles 4 of the 8 H-chunks, atomicAdd into out.
// ---------------------------------------------------------------------------
__global__ __launch_bounds__(256) void k_shared_out(
    const float* __restrict__ hbuf, const float* __restrict__ Ws2, const float* __restrict__ bs2,
    float* __restrict__ out)
{
  __shared__ float hsl[32][256];  // 32 KiB
  const int tid = threadIdx.x;
  const int t0  = blockIdx.x * 32;
  const int cb  = blockIdx.y;     // 0 or 1: H-chunk halves

  float acc0[32], acc1v[32];
  #pragma unroll
  for (int m = 0; m < 32; m++){ acc0[m] = 0.f; acc1v[m] = 0.f; }

  for (int ci = 0; ci < 4; ci++){
    const int ck = cb*4 + ci;
    __syncthreads();
    for (int i = tid; i < 32*64; i += 256){
      const int m = i >> 6, c4 = i & 63;
      reinterpret_cast<float4*>(&hsl[m][0])[c4] =
        reinterpret_cast<const float4*>(hbuf + (size_t)(t0+m)*HSH + ck*256)[c4];
    }
    __syncthreads();
    for (int h4 = 0; h4 < 64; h4++){
      const int h = ck*256 + h4*4;
      const float w00 = Ws2[(size_t)(h+0)*DM + tid];
      const float w01 = Ws2[(size_t)(h+1)*DM + tid];
      const float w02 = Ws2[(size_t)(h+2)*DM + tid];
      const float w03 = Ws2[(size_t)(h+3)*DM + tid];
      const float w10 = Ws2[(size_t)(h+0)*DM + tid+256];
      const float w11 = Ws2[(size_t)(h+1)*DM + tid+256];
      const float w12 = Ws2[(size_t)(h+2)*DM + tid+256];
      const float w13 = Ws2[(size_t)(h+3)*DM + tid+256];
      #pragma unroll
      for (int m = 0; m < 32; m++){
        const float4 hv = reinterpret_cast<const float4*>(&hsl[m][0])[h4];
        acc0[m]  += hv.x*w00 + hv.y*w01 + hv.z*w02 + hv.w*w03;
        acc1v[m] += hv.x*w10 + hv.y*w11 + hv.z*w12 + hv.w*w13;
      }
    }
  }
  const float badd0 = (cb == 0) ? bs2[tid]     : 0.f;
  const float badd1 = (cb == 0) ? bs2[tid+256] : 0.f;
  #pragma unroll
  for (int m = 0; m < 32; m++){
    atomicAdd(&out[(size_t)(t0+m)*DM + tid],       acc0[m]  + badd0);
    atomicAdd(&out[(size_t)(t0+m)*DM + tid + 256], acc1v[m] + badd1);
  }
}

// ---------------------------------------------------------------------------
// Kernel 5: routed experts (grouped GEMM). grid (128 tiles, 64 experts).
// Per block: up to 32 tokens of one expert; fused w1/w3 GEMM + SwiGLU + w2
// GEMM; atomicAdd weighted result into out.
// ---------------------------------------------------------------------------
__global__ __launch_bounds__(256) void k_routed(
    const float* __restrict__ nx, const float* __restrict__ gamma, const float* __restrict__ beta,
    const float* __restrict__ W1, const float* __restrict__ b1,
    const float* __restrict__ W3, const float* __restrict__ b3,
    const float* __restrict__ W2, const float* __restrict__ b2,
    const int* __restrict__ offs, const int* __restrict__ bucket_tok,
    const float* __restrict__ bucket_w, float* __restrict__ out)
{
  const int e = blockIdx.y;
  const int start = offs[e], end = offs[e+1];
  const int b0 = start + blockIdx.x*32;
  int nt = end - b0;
  if (nt <= 0) return;
  if (nt > 32) nt = 32;

  __shared__ float xs[32][DM];    // 64 KiB
  __shared__ float hsc[32][HE];   // 32 KiB
  __shared__ int   toks[32];
  __shared__ float tw[32];
  const int tid = threadIdx.x;

  if (tid < 32){
    if (tid < nt){ toks[tid] = bucket_tok[b0+tid]; tw[tid] = bucket_w[b0+tid]; }
    else         { toks[tid] = 0; tw[tid] = 0.f; }
  }
  __syncthreads();

  // stage expert input: nx * gamma_e + beta_e (rows >= nt zeroed)
  for (int i = tid; i < 32*(DM/4); i += 256){
    const int m = i >> 7, d4 = i & 127;
    float4 v;
    if (m < nt){
      const float4 xv = reinterpret_cast<const float4*>(nx + (size_t)toks[m]*DM)[d4];
      const float4 g  = reinterpret_cast<const float4*>(gamma + (size_t)e*DM)[d4];
      const float4 bb = reinterpret_cast<const float4*>(beta  + (size_t)e*DM)[d4];
      v.x = xv.x*g.x + bb.x; v.y = xv.y*g.y + bb.y; v.z = xv.z*g.z + bb.z; v.w = xv.w*g.w + bb.w;
    } else { v.x = v.y = v.z = v.w = 0.f; }
    reinterpret_cast<float4*>(&xs[m][0])[d4] = v;
  }
  __syncthreads();

  // GEMM1 + GEMM3: each thread owns h-column tid
  const float* W1e = W1 + (size_t)e*DM*HE;
  const float* W3e = W3 + (size_t)e*DM*HE;
  float acc1[32], acc3[32];
  #pragma unroll
  for (int m = 0; m < 32; m++){ acc1[m] = 0.f; acc3[m] = 0.f; }
  for (int d4 = 0; d4 < DM/4; d4++){
    const int d = d4*4;
    const float a0 = W1e[(size_t)(d+0)*HE + tid];
    const float a1 = W1e[(size_t)(d+1)*HE + tid];
    const float a2 = W1e[(size_t)(d+2)*HE + tid];
    const float a3 = W1e[(size_t)(d+3)*HE + tid];
    const float c0 = W3e[(size_t)(d+0)*HE + tid];
    const float c1 = W3e[(size_t)(d+1)*HE + tid];
    const float c2 = W3e[(size_t)(d+2)*HE + tid];
    const float c3 = W3e[(size_t)(d+3)*HE + tid];
    #pragma unroll
    for (int m = 0; m < 32; m++){
      const float4 xv = reinterpret_cast<const float4*>(&xs[m][0])[d4];
      acc1[m] += xv.x*a0 + xv.y*a1 + xv.z*a2 + xv.w*a3;
      acc3[m] += xv.x*c0 + xv.y*c1 + xv.z*c2 + xv.w*c3;
    }
  }
  const float b1v = b1[(size_t)e*HE + tid];
  const float b3v = b3[(size_t)e*HE + tid];
  #pragma unroll
  for (int m = 0; m < 32; m++){
    const float h1 = acc1[m] + b1v;
    const float h3 = acc3[m] + b3v;
    hsc[m][tid] = h1 * sig_(h1) * h3 * tw[m];   // routing weight folded in
  }
  __syncthreads();

  // GEMM2: each thread owns output columns tid and tid+256
  const float* W2e = W2 + (size_t)e*HE*DM;
  float o0[32], o1[32];
  #pragma unroll
  for (int m = 0; m < 32; m++){ o0[m] = 0.f; o1[m] = 0.f; }
  for (int h4 = 0; h4 < HE/4; h4++){
    const int h = h4*4;
    const float w00 = W2e[(size_t)(h+0)*DM + tid];
    const float w01 = W2e[(size_t)(h+1)*DM + tid];
    const float w02 = W2e[(size_t)(h+2)*DM + tid];
    const float w03 = W2e[(size_t)(h+3)*DM + tid];
    const float w10 = W2e[(size_t)(h+0)*DM + tid+256];
    const float w11 = W2e[(size_t)(h+1)*DM + tid+256];
    const float w12 = W2e[(size_t)(h+2)*DM + tid+256];
    const float w13 = W2e[(size_t)(h+3)*DM + tid+256];
    #pragma unroll
    for (int m = 0; m < 32; m++){
      const float4 hv = reinterpret_cast<const float4*>(&hsc[m][0])[h4];
      o0[m] += hv.x*w00 + hv.y*w01 + hv.z*w02 + hv.w*w03;
      o1[m] += hv.x*w10 + hv.y*w11 + hv.z*w12 + hv.w*w13;
    }
  }
  #pragma unroll
  for (int m = 0; m < 32; m++){
    if (m < nt){
      const int t = toks[m];
      const float wm = tw[m];
      atomicAdd(&out[(size_t)t*DM + tid],       o0[m] + wm*b2[(size_t)e*DM + tid]);
      atomicAdd(&out[(size_t)t*DM + tid + 256], o1[m] + wm*b2[(size_t)e*DM + tid + 256]);
    }
  }
}

// ---------------------------------------------------------------------------
extern "C" void kernel_launch(void* const* d_in, const int* in_sizes, int n_in,
                              void* d_out, int out_size, void* d_ws, size_t ws_size,
                              hipStream_t stream)
{
  (void)in_sizes; (void)n_in; (void)ws_size;
  const float* x     = (const float*)d_in[0];
  const float* Wg    = (const float*)d_in[1];
  const float* bg    = (const float*)d_in[2];
  const float* gamma = (const float*)d_in[3];
  const float* beta  = (const float*)d_in[4];
  const float* W1    = (const float*)d_in[5];
  const float* b1    = (const float*)d_in[6];
  const float* W3    = (const float*)d_in[7];
  const float* b3    = (const float*)d_in[8];
  const float* W2    = (const float*)d_in[9];
  const float* b2    = (const float*)d_in[10];
  const float* gs    = (const float*)d_in[11];
  const float* bs    = (const float*)d_in[12];
  const float* Ws1   = (const float*)d_in[13];
  const float* bs1   = (const float*)d_in[14];
  const float* Ws3   = (const float*)d_in[15];
  const float* bs3   = (const float*)d_in[16];
  const float* Ws2   = (const float*)d_in[17];
  const float* bs2   = (const float*)d_in[18];
  float* out = (float*)d_out;

  char* ws = (char*)d_ws;
  size_t off = 0;
  float* nx        = (float*)(ws + off); off += (size_t)TT*DM*sizeof(float);
  int*   top_idx   = (int*)  (ws + off); off += (size_t)TT*TOPK*sizeof(int);
  float* top_w     = (float*)(ws + off); off += (size_t)TT*TOPK*sizeof(float);
  int*   offs      = (int*)  (ws + off); off += 128*sizeof(int);
  int*   bucket_tok= (int*)  (ws + off); off += (size_t)TT*TOPK*sizeof(int);
  float* bucket_w  = (float*)(ws + off); off += (size_t)TT*TOPK*sizeof(float);
  float* hbuf      = (float*)(ws + off); off += (size_t)TT*HSH*sizeof(float);

  hipMemsetAsync(d_out, 0, (size_t)out_size*sizeof(float), stream);
  k_ln_gate<<<dim3(TT), dim3(256), 0, stream>>>(x, Wg, bg, nx, top_idx, top_w);
  k_route<<<dim3(1), dim3(256), 0, stream>>>(top_idx, top_w, offs, bucket_tok, bucket_w);
  k_shared_h<<<dim3(TT/32, HSH/256), dim3(256), 0, stream>>>(nx, gs, bs, Ws1, bs1, Ws3, bs3, hbuf);
  k_shared_out<<<dim3(TT/32, 2), dim3(256), 0, stream>>>(hbuf, Ws2, bs2, out);
  k_routed<<<dim3(TT/32, NE), dim3(256), 0, stream>>>(nx, gamma, beta, W1, b1, W3, b3, W2, b2,
                                                      offs, bucket_tok, bucket_w, out);
}

// Round 2
// 866.384 us; speedup vs baseline: 3.1963x; 3.1963x over previous
//
#include <hip/hip_runtime.h>
#include <hip/hip_bf16.h>
#include <math.h>

#define TT   4096   // tokens
#define DM   512    // model dim
#define NE   64     // routed experts
#define TOPK 2
#define HE   256    // expert hidden
#define HSH  2048   // shared expert hidden
#define MAXTILES 320  // sum ceil(cnt_e/32) <= 8192/32 + 64

__device__ __forceinline__ float sig_(float z){ return 1.f/(1.f+__expf(-z)); }

// ---------------------------------------------------------------------------
// Kernel 1: per-token LayerNorm stats + nx, gate logits + top-2 selection.
// ---------------------------------------------------------------------------
__global__ __launch_bounds__(256) void k_ln_gate(
    const float* __restrict__ x, const float* __restrict__ Wg, const float* __restrict__ bg,
    float* __restrict__ nx, int* __restrict__ top_idx, float* __restrict__ top_w)
{
  __shared__ float xs[DM];
  __shared__ float sred[4], ssred[4];
  __shared__ float sc[NE];
  const int tid = threadIdx.x;
  const int t   = blockIdx.x;

  float2 v = reinterpret_cast<const float2*>(x + (size_t)t*DM)[tid];
  xs[2*tid]   = v.x;
  xs[2*tid+1] = v.y;
  float s  = v.x + v.y;
  float ss = v.x*v.x + v.y*v.y;
  #pragma unroll
  for (int o = 32; o > 0; o >>= 1){ s += __shfl_xor(s, o); ss += __shfl_xor(ss, o); }
  const int wid = tid >> 6, lane = tid & 63;
  if (lane == 0){ sred[wid] = s; ssred[wid] = ss; }
  __syncthreads();
  const float tot = sred[0]+sred[1]+sred[2]+sred[3];
  const float tss = ssred[0]+ssred[1]+ssred[2]+ssred[3];
  const float mu  = tot * (1.f/DM);
  const float var = tss * (1.f/DM) - mu*mu;
  const float rstd = rsqrtf(var + 1e-5f);
  float2 nv; nv.x = (v.x-mu)*rstd; nv.y = (v.y-mu)*rstd;
  reinterpret_cast<float2*>(nx + (size_t)t*DM)[tid] = nv;

  // gate logits: 4 threads per expert, float4 loads
  const int e = tid >> 2, sub = tid & 3;
  const float4* wrow4 = reinterpret_cast<const float4*>(Wg + (size_t)e*DM);
  const float4* xs4   = reinterpret_cast<const float4*>(xs);
  float acc = 0.f;
  #pragma unroll 4
  for (int i = sub; i < DM/4; i += 4){
    const float4 w = wrow4[i]; const float4 xv = xs4[i];
    acc += xv.x*w.x + xv.y*w.y + xv.z*w.z + xv.w*w.w;
  }
  acc += __shfl_xor(acc, 1);
  acc += __shfl_xor(acc, 2);
  if (sub == 0) sc[e] = acc + bg[e];
  __syncthreads();

  if (tid < 64) {
    const float s0 = sc[tid];
    float m = s0; int mi = tid;
    #pragma unroll
    for (int o = 1; o < 64; o <<= 1){
      float om = __shfl_xor(m, o); int oi = __shfl_xor(mi, o);
      if (om > m || (om == m && oi < mi)) { m = om; mi = oi; }
    }
    float s1 = (tid == mi) ? -INFINITY : s0;
    float m2 = s1; int mi2 = tid;
    #pragma unroll
    for (int o = 1; o < 64; o <<= 1){
      float om = __shfl_xor(m2, o); int oi = __shfl_xor(mi2, o);
      if (om > m2 || (om == m2 && oi < mi2)) { m2 = om; mi2 = oi; }
    }
    if (tid == 0){
      const float w0 = sig_(m), w1 = sig_(m2);
      const float inv = 1.f/(w0+w1);
      top_idx[2*t]   = mi;
      top_idx[2*t+1] = mi2;
      top_w[2*t]     = w0*inv;
      top_w[2*t+1]   = w1*inv;
    }
  }
}

// ---------------------------------------------------------------------------
// Kernel 2: routing — counts, scan, scatter, and COMPACT TILE WORKLIST.
// ---------------------------------------------------------------------------
__global__ __launch_bounds__(256) void k_route(
    const int* __restrict__ top_idx, const float* __restrict__ top_w,
    int* __restrict__ bucket_tok, float* __restrict__ bucket_w,
    int* __restrict__ tiles, int* __restrict__ n_tiles)
{
  __shared__ int cnt[NE], base_[NE];
  const int tid = threadIdx.x;
  if (tid < NE) cnt[tid] = 0;
  __syncthreads();
  for (int p = tid; p < TT*TOPK; p += 256) atomicAdd(&cnt[top_idx[p]], 1);
  __syncthreads();
  if (tid == 0){
    int run = 0, ntl = 0;
    for (int e = 0; e < NE; e++){
      base_[e] = run;
      const int c = cnt[e];
      for (int b = 0; b < c; b += 32){
        const int n = (c - b < 32) ? (c - b) : 32;
        tiles[ntl++] = (e << 20) | ((run + b) << 6) | n;   // e:6b | b0:14b | nt:6b
      }
      run += c;
    }
    *n_tiles = ntl;
  }
  __syncthreads();
  if (tid < NE) cnt[tid] = 0;
  __syncthreads();
  for (int p = tid; p < TT*TOPK; p += 256){
    const int e = top_idx[p];
    const int pos = base_[e] + atomicAdd(&cnt[e], 1);
    bucket_tok[pos] = p >> 1;
    bucket_w[pos]   = top_w[p];
  }
}

// ---------------------------------------------------------------------------
// Kernel 3: routed up-proj (worklist): hrout[slot] = swiglu(xs@W1p, xs@W3p)*tw
// ---------------------------------------------------------------------------
__global__ __launch_bounds__(256) void k_up(
    const float* __restrict__ nx, const float* __restrict__ gamma, const float* __restrict__ beta,
    const float* __restrict__ W1, const float* __restrict__ b1,
    const float* __restrict__ W3, const float* __restrict__ b3,
    const int* __restrict__ bucket_tok, const float* __restrict__ bucket_w,
    const int* __restrict__ tiles, const int* __restrict__ n_tiles,
    float* __restrict__ hrout)
{
  if ((int)blockIdx.x >= *n_tiles) return;
  const int info = tiles[blockIdx.x];
  const int e  = info >> 20;
  const int b0 = (info >> 6) & 0x3FFF;
  const int nt = info & 63;

  __shared__ float xs[32][DM];    // 64 KiB
  __shared__ int   toks[32];
  __shared__ float tw[32];
  const int tid = threadIdx.x;

  if (tid < 32){
    if (tid < nt){ toks[tid] = bucket_tok[b0+tid]; tw[tid] = bucket_w[b0+tid]; }
    else         { toks[tid] = 0; tw[tid] = 0.f; }
  }
  __syncthreads();

  for (int i = tid; i < 32*(DM/4); i += 256){
    const int m = i >> 7, d4 = i & 127;
    float4 v;
    if (m < nt){
      const float4 xv = reinterpret_cast<const float4*>(nx + (size_t)toks[m]*DM)[d4];
      const float4 g  = reinterpret_cast<const float4*>(gamma + (size_t)e*DM)[d4];
      const float4 bb = reinterpret_cast<const float4*>(beta  + (size_t)e*DM)[d4];
      v.x = xv.x*g.x + bb.x; v.y = xv.y*g.y + bb.y; v.z = xv.z*g.z + bb.z; v.w = xv.w*g.w + bb.w;
    } else { v.x = v.y = v.z = v.w = 0.f; }
    reinterpret_cast<float4*>(&xs[m][0])[d4] = v;
  }
  __syncthreads();

  const float* W1e = W1 + (size_t)e*DM*HE;
  const float* W3e = W3 + (size_t)e*DM*HE;
  float acc1[32], acc3[32];
  #pragma unroll
  for (int m = 0; m < 32; m++){ acc1[m] = 0.f; acc3[m] = 0.f; }
  for (int d4 = 0; d4 < DM/4; d4++){
    const int d = d4*4;
    const float a0 = W1e[(size_t)(d+0)*HE + tid];
    const float a1 = W1e[(size_t)(d+1)*HE + tid];
    const float a2 = W1e[(size_t)(d+2)*HE + tid];
    const float a3 = W1e[(size_t)(d+3)*HE + tid];
    const float c0 = W3e[(size_t)(d+0)*HE + tid];
    const float c1 = W3e[(size_t)(d+1)*HE + tid];
    const float c2 = W3e[(size_t)(d+2)*HE + tid];
    const float c3 = W3e[(size_t)(d+3)*HE + tid];
    #pragma unroll
    for (int m = 0; m < 32; m++){
      const float4 xv = reinterpret_cast<const float4*>(&xs[m][0])[d4];
      acc1[m] += xv.x*a0 + xv.y*a1 + xv.z*a2 + xv.w*a3;
      acc3[m] += xv.x*c0 + xv.y*c1 + xv.z*c2 + xv.w*c3;
    }
  }
  const float b1v = b1[(size_t)e*HE + tid];
  const float b3v = b3[(size_t)e*HE + tid];
  #pragma unroll
  for (int m = 0; m < 32; m++){
    if (m < nt){
      const float h1 = acc1[m] + b1v;
      const float h3 = acc3[m] + b3v;
      hrout[(size_t)(b0+m)*HE + tid] = h1 * sig_(h1) * h3 * tw[m];
    }
  }
}

// ---------------------------------------------------------------------------
// Kernel 4: routed down-proj (worklist): out[tok] += hrout[slot]@W2[e] + tw*b2
// ---------------------------------------------------------------------------
__global__ __launch_bounds__(256) void k_down(
    const float* __restrict__ hrout, const float* __restrict__ W2, const float* __restrict__ b2,
    const int* __restrict__ bucket_tok, const float* __restrict__ bucket_w,
    const int* __restrict__ tiles, const int* __restrict__ n_tiles,
    float* __restrict__ out)
{
  if ((int)blockIdx.x >= *n_tiles) return;
  const int info = tiles[blockIdx.x];
  const int e  = info >> 20;
  const int b0 = (info >> 6) & 0x3FFF;
  const int nt = info & 63;

  __shared__ float hsl[32][HE];   // 32 KiB
  __shared__ int   toks[32];
  __shared__ float tw[32];
  const int tid = threadIdx.x;

  if (tid < 32){
    if (tid < nt){ toks[tid] = bucket_tok[b0+tid]; tw[tid] = bucket_w[b0+tid]; }
    else         { toks[tid] = 0; tw[tid] = 0.f; }
  }
  __syncthreads();

  for (int i = tid; i < 32*(HE/4); i += 256){
    const int m = i >> 6, c4 = i & 63;
    float4 v;
    if (m < nt) v = reinterpret_cast<const float4*>(hrout + (size_t)(b0+m)*HE)[c4];
    else        { v.x = v.y = v.z = v.w = 0.f; }
    reinterpret_cast<float4*>(&hsl[m][0])[c4] = v;
  }
  __syncthreads();

  const float* W2e = W2 + (size_t)e*HE*DM;
  float o0[32], o1[32];
  #pragma unroll
  for (int m = 0; m < 32; m++){ o0[m] = 0.f; o1[m] = 0.f; }
  for (int h4 = 0; h4 < HE/4; h4++){
    const int h = h4*4;
    const float w00 = W2e[(size_t)(h+0)*DM + tid];
    const float w01 = W2e[(size_t)(h+1)*DM + tid];
    const float w02 = W2e[(size_t)(h+2)*DM + tid];
    const float w03 = W2e[(size_t)(h+3)*DM + tid];
    const float w10 = W2e[(size_t)(h+0)*DM + tid+256];
    const float w11 = W2e[(size_t)(h+1)*DM + tid+256];
    const float w12 = W2e[(size_t)(h+2)*DM + tid+256];
    const float w13 = W2e[(size_t)(h+3)*DM + tid+256];
    #pragma unroll
    for (int m = 0; m < 32; m++){
      const float4 hv = reinterpret_cast<const float4*>(&hsl[m][0])[h4];
      o0[m] += hv.x*w00 + hv.y*w01 + hv.z*w02 + hv.w*w03;
      o1[m] += hv.x*w10 + hv.y*w11 + hv.z*w12 + hv.w*w13;
    }
  }
  #pragma unroll
  for (int m = 0; m < 32; m++){
    if (m < nt){
      const int t = toks[m];
      const float wm = tw[m];
      atomicAdd(&out[(size_t)t*DM + tid],       o0[m] + wm*b2[(size_t)e*DM + tid]);
      atomicAdd(&out[(size_t)t*DM + tid + 256], o1[m] + wm*b2[(size_t)e*DM + tid + 256]);
    }
  }
}

// ---------------------------------------------------------------------------
// Kernel 5: shared expert up-proj
// ---------------------------------------------------------------------------
__global__ __launch_bounds__(256) void k_shared_h(
    const float* __restrict__ nx, const float* __restrict__ gs, const float* __restrict__ bs,
    const float* __restrict__ Ws1, const float* __restrict__ bs1,
    const float* __restrict__ Ws3, const float* __restrict__ bs3,
    float* __restrict__ hbuf)
{
  __shared__ float xs[32][DM];   // 64 KiB
  const int tid  = threadIdx.x;
  const int t0   = blockIdx.x * 32;
  const int hcol = blockIdx.y * 256 + tid;

  for (int i = tid; i < 32*(DM/4); i += 256){
    const int m = i >> 7, d4 = i & 127;
    float4 v = reinterpret_cast<const float4*>(nx + (size_t)(t0+m)*DM)[d4];
    const float4 g = reinterpret_cast<const float4*>(gs)[d4];
    const float4 b = reinterpret_cast<const float4*>(bs)[d4];
    v.x = v.x*g.x + b.x; v.y = v.y*g.y + b.y; v.z = v.z*g.z + b.z; v.w = v.w*g.w + b.w;
    reinterpret_cast<float4*>(&xs[m][0])[d4] = v;
  }
  __syncthreads();

  float acc1[32], acc3[32];
  #pragma unroll
  for (int m = 0; m < 32; m++){ acc1[m] = 0.f; acc3[m] = 0.f; }

  for (int d4 = 0; d4 < DM/4; d4++){
    const int d = d4*4;
    const float a0 = Ws1[(size_t)(d+0)*HSH + hcol];
    const float a1 = Ws1[(size_t)(d+1)*HSH + hcol];
    const float a2 = Ws1[(size_t)(d+2)*HSH + hcol];
    const float a3 = Ws1[(size_t)(d+3)*HSH + hcol];
    const float c0 = Ws3[(size_t)(d+0)*HSH + hcol];
    const float c1 = Ws3[(size_t)(d+1)*HSH + hcol];
    const float c2 = Ws3[(size_t)(d+2)*HSH + hcol];
    const float c3 = Ws3[(size_t)(d+3)*HSH + hcol];
    #pragma unroll
    for (int m = 0; m < 32; m++){
      const float4 xv = reinterpret_cast<const float4*>(&xs[m][0])[d4];
      acc1[m] += xv.x*a0 + xv.y*a1 + xv.z*a2 + xv.w*a3;
      acc3[m] += xv.x*c0 + xv.y*c1 + xv.z*c2 + xv.w*c3;
    }
  }
  const float b1v = bs1[hcol], b3v = bs3[hcol];
  #pragma unroll
  for (int m = 0; m < 32; m++){
    const float h1 = acc1[m] + b1v;
    const float h3 = acc3[m] + b3v;
    hbuf[(size_t)(t0+m)*HSH + hcol] = h1 * sig_(h1) * h3;
  }
}

// ---------------------------------------------------------------------------
// Kernel 6: shared expert down-proj, one 256-wide H-chunk per block.
// grid (T/32, 8); atomicAdd partial into out; bias added by ck==0 blocks.
// ---------------------------------------------------------------------------
__global__ __launch_bounds__(256) void k_shared_out(
    const float* __restrict__ hbuf, const float* __restrict__ Ws2, const float* __restrict__ bs2,
    float* __restrict__ out)
{
  __shared__ float hsl[32][256];  // 32 KiB
  const int tid = threadIdx.x;
  const int t0  = blockIdx.x * 32;
  const int ck  = blockIdx.y;     // H-chunk 0..7

  for (int i = tid; i < 32*64; i += 256){
    const int m = i >> 6, c4 = i & 63;
    reinterpret_cast<float4*>(&hsl[m][0])[c4] =
      reinterpret_cast<const float4*>(hbuf + (size_t)(t0+m)*HSH + ck*256)[c4];
  }
  __syncthreads();

  float acc0[32], acc1v[32];
  #pragma unroll
  for (int m = 0; m < 32; m++){ acc0[m] = 0.f; acc1v[m] = 0.f; }

  for (int h4 = 0; h4 < 64; h4++){
    const int h = ck*256 + h4*4;
    const float w00 = Ws2[(size_t)(h+0)*DM + tid];
    const float w01 = Ws2[(size_t)(h+1)*DM + tid];
    const float w02 = Ws2[(size_t)(h+2)*DM + tid];
    const float w03 = Ws2[(size_t)(h+3)*DM + tid];
    const float w10 = Ws2[(size_t)(h+0)*DM + tid+256];
    const float w11 = Ws2[(size_t)(h+1)*DM + tid+256];
    const float w12 = Ws2[(size_t)(h+2)*DM + tid+256];
    const float w13 = Ws2[(size_t)(h+3)*DM + tid+256];
    #pragma unroll
    for (int m = 0; m < 32; m++){
      const float4 hv = reinterpret_cast<const float4*>(&hsl[m][0])[h4];
      acc0[m]  += hv.x*w00 + hv.y*w01 + hv.z*w02 + hv.w*w03;
      acc1v[m] += hv.x*w10 + hv.y*w11 + hv.z*w12 + hv.w*w13;
    }
  }
  const float badd0 = (ck == 0) ? bs2[tid]     : 0.f;
  const float badd1 = (ck == 0) ? bs2[tid+256] : 0.f;
  #pragma unroll
  for (int m = 0; m < 32; m++){
    atomicAdd(&out[(size_t)(t0+m)*DM + tid],       acc0[m]  + badd0);
    atomicAdd(&out[(size_t)(t0+m)*DM + tid + 256], acc1v[m] + badd1);
  }
}

// ---------------------------------------------------------------------------
extern "C" void kernel_launch(void* const* d_in, const int* in_sizes, int n_in,
                              void* d_out, int out_size, void* d_ws, size_t ws_size,
                              hipStream_t stream)
{
  (void)in_sizes; (void)n_in; (void)ws_size;
  const float* x     = (const float*)d_in[0];
  const float* Wg    = (const float*)d_in[1];
  const float* bg    = (const float*)d_in[2];
  const float* gamma = (const float*)d_in[3];
  const float* beta  = (const float*)d_in[4];
  const float* W1    = (const float*)d_in[5];
  const float* b1    = (const float*)d_in[6];
  const float* W3    = (const float*)d_in[7];
  const float* b3    = (const float*)d_in[8];
  const float* W2    = (const float*)d_in[9];
  const float* b2    = (const float*)d_in[10];
  const float* gs    = (const float*)d_in[11];
  const float* bs    = (const float*)d_in[12];
  const float* Ws1   = (const float*)d_in[13];
  const float* bs1   = (const float*)d_in[14];
  const float* Ws3   = (const float*)d_in[15];
  const float* bs3   = (const float*)d_in[16];
  const float* Ws2   = (const float*)d_in[17];
  const float* bs2   = (const float*)d_in[18];
  float* out = (float*)d_out;

  char* ws = (char*)d_ws;
  size_t off = 0;
  float* nx        = (float*)(ws + off); off += (size_t)TT*DM*sizeof(float);
  int*   top_idx   = (int*)  (ws + off); off += (size_t)TT*TOPK*sizeof(int);
  float* top_w     = (float*)(ws + off); off += (size_t)TT*TOPK*sizeof(float);
  int*   bucket_tok= (int*)  (ws + off); off += (size_t)TT*TOPK*sizeof(int);
  float* bucket_w  = (float*)(ws + off); off += (size_t)TT*TOPK*sizeof(float);
  int*   tiles     = (int*)  (ws + off); off += (size_t)MAXTILES*sizeof(int);
  int*   n_tiles   = (int*)  (ws + off); off += 64;  // keep hbuf aligned
  float* hbuf      = (float*)(ws + off); off += (size_t)TT*HSH*sizeof(float);
  float* hrout     = hbuf;  // routed intermediate reuses hbuf (stream-ordered before k_shared_h)

  hipMemsetAsync(d_out, 0, (size_t)out_size*sizeof(float), stream);
  k_ln_gate<<<dim3(TT), dim3(256), 0, stream>>>(x, Wg, bg, nx, top_idx, top_w);
  k_route<<<dim3(1), dim3(256), 0, stream>>>(top_idx, top_w, bucket_tok, bucket_w, tiles, n_tiles);
  k_up<<<dim3(MAXTILES), dim3(256), 0, stream>>>(nx, gamma, beta, W1, b1, W3, b3,
                                                 bucket_tok, bucket_w, tiles, n_tiles, hrout);
  k_down<<<dim3(MAXTILES), dim3(256), 0, stream>>>(hrout, W2, b2, bucket_tok, bucket_w,
                                                   tiles, n_tiles, out);
  k_shared_h<<<dim3(TT/32, HSH/256), dim3(256), 0, stream>>>(nx, gs, bs, Ws1, bs1, Ws3, bs3, hbuf);
  k_shared_out<<<dim3(TT/32, HSH/256), dim3(256), 0, stream>>>(hbuf, Ws2, bs2, out);
}

// Round 3
// 364.466 us; speedup vs baseline: 7.5981x; 2.3771x over previous
//
#include <hip/hip_runtime.h>
#include <math.h>

typedef unsigned short u16;
typedef __attribute__((ext_vector_type(8))) short bf16x8;
typedef __attribute__((ext_vector_type(4))) float f32x4;

#define TT   4096   // tokens
#define DM   512    // model dim
#define NE   64     // routed experts
#define HE   256    // expert hidden
#define HSH  2048   // shared expert hidden
#define MAXTILES 320

__device__ __forceinline__ float sig_(float z){ return 1.f/(1.f+__expf(-z)); }

__device__ __forceinline__ u16 f2bf(float x){
  unsigned int u = __builtin_bit_cast(unsigned int, x);
  u = (u + 0x7FFFu + ((u >> 16) & 1u)) >> 16;
  return (u16)u;
}

__device__ __forceinline__ f32x4 mfma16(bf16x8 a, bf16x8 b, f32x4 c){
  return __builtin_amdgcn_mfma_f32_16x16x32_bf16(a, b, c, 0, 0, 0);
}

// read one A/B fragment: 8 contiguous bf16 along k (m97 convention)
// tile: row-major [rows][32k] = 64 bytes per row
__device__ __forceinline__ bf16x8 frd(const char* tile, int row, int q){
  return *(const bf16x8*)(tile + row*64 + q*16);
}

// ---------------------------------------------------------------------------
// Pre-pass A: transpose-convert fp32 [K][N] -> bf16 [N][K], optional row scale.
// grid (K/64, N/64, nmat); scale = per-mat K floats (or nullptr).
// ---------------------------------------------------------------------------
__global__ __launch_bounds__(256) void k_cvtT(
    const float* __restrict__ in, const float* __restrict__ scale,
    u16* __restrict__ out, int K, int N)
{
  __shared__ u16 T[64][80];  // 16B-aligned row stride
  const int tid = threadIdx.x;
  const int k0 = blockIdx.x*64, n0 = blockIdx.y*64;
  const size_t moff = (size_t)blockIdx.z * K * N;
  in  += moff; out += moff;
  const int r = tid>>2, cb = (tid&3)*16;
  const float sc = scale ? scale[(size_t)blockIdx.z*K + k0 + r] : 1.0f;
  #pragma unroll
  for (int j = 0; j < 4; j++){
    float4 v = *(const float4*)(in + (size_t)(k0+r)*N + n0 + cb + j*4);
    T[cb+j*4+0][r] = f2bf(v.x*sc);
    T[cb+j*4+1][r] = f2bf(v.y*sc);
    T[cb+j*4+2][r] = f2bf(v.z*sc);
    T[cb+j*4+3][r] = f2bf(v.w*sc);
  }
  __syncthreads();
  const int n = tid>>2, kb = (tid&3)*16;
  uint4 a = *(const uint4*)&T[n][kb];
  uint4 b = *(const uint4*)&T[n][kb+8];
  *(uint4*)(out + (size_t)(n0+n)*K + k0 + kb)     = a;
  *(uint4*)(out + (size_t)(n0+n)*K + k0 + kb + 8) = b;
}

// ---------------------------------------------------------------------------
// Pre-pass B: routed bias fold: b1p[e][h] = b1[e][h] + sum_d beta[e][d]*W1[e][d][h]
// grid (NE, 2)
// ---------------------------------------------------------------------------
__global__ __launch_bounds__(256) void k_fold_rout(
    const float* __restrict__ W1, const float* __restrict__ W3,
    const float* __restrict__ b1, const float* __restrict__ b3,
    const float* __restrict__ beta, float* __restrict__ b1p, float* __restrict__ b3p)
{
  const int e = blockIdx.x, mat = blockIdx.y;
  const float* W   = mat ? W3 : W1;
  const float* bin = mat ? b3 : b1;
  float* bout      = mat ? b3p : b1p;
  __shared__ float bet[DM];
  for (int i = threadIdx.x; i < DM; i += 256) bet[i] = beta[(size_t)e*DM + i];
  __syncthreads();
  const int h = threadIdx.x;
  float acc = bin[(size_t)e*HE + h];
  const float* We = W + (size_t)e*DM*HE;
  #pragma unroll 4
  for (int d = 0; d < DM; d++) acc += bet[d] * We[(size_t)d*HE + h];
  bout[(size_t)e*HE + h] = acc;
}

// ---------------------------------------------------------------------------
// Pre-pass C: shared bias fold: o1[h] (+)= chunk-partial of sum_d bs[d]*Ws1[d][h]
// grid (8, 2); o1/o3 must be zeroed first; chunk 0 adds bias_in.
// ---------------------------------------------------------------------------
__global__ __launch_bounds__(256) void k_fold_shared(
    const float* __restrict__ Ws1, const float* __restrict__ Ws3,
    const float* __restrict__ bs1, const float* __restrict__ bs3,
    const float* __restrict__ bsv, float* __restrict__ o1, float* __restrict__ o3)
{
  const int mat = blockIdx.y;
  const float* W   = mat ? Ws3 : Ws1;
  const float* bin = mat ? bs3 : bs1;
  float* out       = mat ? o3 : o1;
  const int c0 = blockIdx.x*64;
  __shared__ float bv[64];
  if (threadIdx.x < 64) bv[threadIdx.x] = bsv[c0 + threadIdx.x];
  __syncthreads();
  for (int h = threadIdx.x; h < HSH; h += 256){
    float acc = 0.f;
    #pragma unroll 4
    for (int d = 0; d < 64; d++) acc += bv[d] * W[(size_t)(c0+d)*HSH + h];
    if (blockIdx.x == 0) acc += bin[h];
    atomicAdd(out + h, acc);
  }
}

// ---------------------------------------------------------------------------
// Kernel 1: per-token LN stats -> nxb (bf16), gate logits + top-2.
// ---------------------------------------------------------------------------
__global__ __launch_bounds__(256) void k_ln_gate(
    const float* __restrict__ x, const float* __restrict__ Wg, const float* __restrict__ bg,
    u16* __restrict__ nxb, int* __restrict__ top_idx, float* __restrict__ top_w)
{
  __shared__ float xs[DM];
  __shared__ float sred[4], ssred[4];
  __shared__ float sc[NE];
  const int tid = threadIdx.x;
  const int t   = blockIdx.x;

  float2 v = reinterpret_cast<const float2*>(x + (size_t)t*DM)[tid];
  xs[2*tid]   = v.x;
  xs[2*tid+1] = v.y;
  float s  = v.x + v.y;
  float ss = v.x*v.x + v.y*v.y;
  #pragma unroll
  for (int o = 32; o > 0; o >>= 1){ s += __shfl_xor(s, o); ss += __shfl_xor(ss, o); }
  const int wid = tid >> 6, lane = tid & 63;
  if (lane == 0){ sred[wid] = s; ssred[wid] = ss; }
  __syncthreads();
  const float tot = sred[0]+sred[1]+sred[2]+sred[3];
  const float tss = ssred[0]+ssred[1]+ssred[2]+ssred[3];
  const float mu  = tot * (1.f/DM);
  const float var = tss * (1.f/DM) - mu*mu;
  const float rstd = rsqrtf(var + 1e-5f);
  unsigned int pk = (unsigned int)f2bf((v.x-mu)*rstd) | ((unsigned int)f2bf((v.y-mu)*rstd) << 16);
  *(unsigned int*)(nxb + (size_t)t*DM + 2*tid) = pk;

  // gate logits: 4 threads per expert, float4 loads
  const int e = tid >> 2, sub = tid & 3;
  const float4* wrow4 = reinterpret_cast<const float4*>(Wg + (size_t)e*DM);
  const float4* xs4   = reinterpret_cast<const float4*>(xs);
  float acc = 0.f;
  #pragma unroll 4
  for (int i = sub; i < DM/4; i += 4){
    const float4 w = wrow4[i]; const float4 xv = xs4[i];
    acc += xv.x*w.x + xv.y*w.y + xv.z*w.z + xv.w*w.w;
  }
  acc += __shfl_xor(acc, 1);
  acc += __shfl_xor(acc, 2);
  if (sub == 0) sc[e] = acc + bg[e];
  __syncthreads();

  if (tid < 64) {
    const float s0 = sc[tid];
    float m = s0; int mi = tid;
    #pragma unroll
    for (int o = 1; o < 64; o <<= 1){
      float om = __shfl_xor(m, o); int oi = __shfl_xor(mi, o);
      if (om > m || (om == m && oi < mi)) { m = om; mi = oi; }
    }
    float s1 = (tid == mi) ? -INFINITY : s0;
    float m2 = s1; int mi2 = tid;
    #pragma unroll
    for (int o = 1; o < 64; o <<= 1){
      float om = __shfl_xor(m2, o); int oi = __shfl_xor(mi2, o);
      if (om > m2 || (om == m2 && oi < mi2)) { m2 = om; mi2 = oi; }
    }
    if (tid == 0){
      const float w0 = sig_(m), w1 = sig_(m2);
      const float inv = 1.f/(w0+w1);
      top_idx[2*t]   = mi;
      top_idx[2*t+1] = mi2;
      top_w[2*t]     = w0*inv;
      top_w[2*t+1]   = w1*inv;
    }
  }
}

// ---------------------------------------------------------------------------
// Kernel 2: routing — counts, scan, scatter, compact tile worklist (M=32).
// ---------------------------------------------------------------------------
__global__ __launch_bounds__(256) void k_route(
    const int* __restrict__ top_idx, const float* __restrict__ top_w,
    int* __restrict__ bucket_tok, float* __restrict__ bucket_w,
    int* __restrict__ tiles, int* __restrict__ n_tiles)
{
  __shared__ int cnt[NE], base_[NE];
  const int tid = threadIdx.x;
  if (tid < NE) cnt[tid] = 0;
  __syncthreads();
  for (int p = tid; p < TT*2; p += 256) atomicAdd(&cnt[top_idx[p]], 1);
  __syncthreads();
  if (tid == 0){
    int run = 0, ntl = 0;
    for (int e = 0; e < NE; e++){
      base_[e] = run;
      const int c = cnt[e];
      for (int b = 0; b < c; b += 32){
        const int n = (c - b < 32) ? (c - b) : 32;
        tiles[ntl++] = (e << 20) | ((run + b) << 6) | n;
      }
      run += c;
    }
    *n_tiles = ntl;
  }
  __syncthreads();
  if (tid < NE) cnt[tid] = 0;
  __syncthreads();
  for (int p = tid; p < TT*2; p += 256){
    const int e = top_idx[p];
    const int pos = base_[e] + atomicAdd(&cnt[e], 1);
    bucket_tok[pos] = p >> 1;
    bucket_w[pos]   = top_w[p];
  }
}

// ---------------------------------------------------------------------------
// Kernel 3: routed up (MFMA): hrout[slot][h] = swiglu(nx@W1p+b1p, nx@W3p+b3p)*tw
// BM=32, BN=256(full HE), K=512, BK=32. 4 waves: each owns 32x64 per matrix.
// ---------------------------------------------------------------------------
__global__ __launch_bounds__(256) void k_up(
    const u16* __restrict__ nxb,
    const u16* __restrict__ W1bT, const u16* __restrict__ W3bT,
    const float* __restrict__ b1p, const float* __restrict__ b3p,
    const int* __restrict__ bucket_tok, const float* __restrict__ bucket_w,
    const int* __restrict__ tiles, const int* __restrict__ n_tiles,
    u16* __restrict__ hrout)
{
  if ((int)blockIdx.x >= *n_tiles) return;
  const int info = tiles[blockIdx.x];
  const int e  = info >> 20;
  const int b0 = (info >> 6) & 0x3FFF;
  const int nt = info & 63;

  __shared__ char As[32*64];
  __shared__ char B1s[256*64];
  __shared__ char B3s[256*64];
  __shared__ int   toks[32];
  __shared__ float tw[32];

  const int tid = threadIdx.x;
  const int wid = tid >> 6, lane = tid & 63;
  const int l15 = lane & 15, q = lane >> 4;
  const int wn = wid * 64;

  if (tid < 32){
    if (tid < nt){ toks[tid] = bucket_tok[b0+tid]; tw[tid] = bucket_w[b0+tid]; }
    else         { toks[tid] = 0; tw[tid] = 0.f; }
  }
  __syncthreads();

  f32x4 acc1[2][4], acc3[2][4];
  #pragma unroll
  for (int fn = 0; fn < 4; fn++){
    const float b1v = b1p[(size_t)e*HE + wn + fn*16 + l15];
    const float b3v = b3p[(size_t)e*HE + wn + fn*16 + l15];
    #pragma unroll
    for (int fm = 0; fm < 2; fm++){
      acc1[fm][fn] = (f32x4){b1v,b1v,b1v,b1v};
      acc3[fm][fn] = (f32x4){b3v,b3v,b3v,b3v};
    }
  }

  const int arow = tid >> 3;              // 0..31
  const int ace  = (tid & 7) * 4;         // element offset 0..28
  const u16* w1e = W1bT + (size_t)e*HE*DM;
  const u16* w3e = W3bT + (size_t)e*HE*DM;

  for (int ks = 0; ks < DM/32; ks++){
    const int k0 = ks*32;
    // A: 32 rows x 32k, gathered by token
    {
      uint2 v = *(const uint2*)(nxb + (size_t)toks[arow]*DM + k0 + ace);
      *(uint2*)(As + arow*64 + ace*2) = v;
    }
    // B1/B3: 256 rows x 32k each; one full row (64B) per thread per matrix
    {
      const u16* g1 = w1e + (size_t)tid*DM + k0;
      const u16* g3 = w3e + (size_t)tid*DM + k0;
      #pragma unroll
      for (int j = 0; j < 4; j++){
        *(uint4*)(B1s + tid*64 + j*16) = *(const uint4*)(g1 + j*8);
        *(uint4*)(B3s + tid*64 + j*16) = *(const uint4*)(g3 + j*8);
      }
    }
    __syncthreads();
    bf16x8 fa0 = frd(As, 0  + l15, q);
    bf16x8 fa1 = frd(As, 16 + l15, q);
    #pragma unroll
    for (int fn = 0; fn < 4; fn++){
      bf16x8 fb1 = frd(B1s, wn + fn*16 + l15, q);
      bf16x8 fb3 = frd(B3s, wn + fn*16 + l15, q);
      acc1[0][fn] = mfma16(fa0, fb1, acc1[0][fn]);
      acc1[1][fn] = mfma16(fa1, fb1, acc1[1][fn]);
      acc3[0][fn] = mfma16(fa0, fb3, acc3[0][fn]);
      acc3[1][fn] = mfma16(fa1, fb3, acc3[1][fn]);
    }
    __syncthreads();
  }

  #pragma unroll
  for (int fm = 0; fm < 2; fm++){
    #pragma unroll
    for (int fn = 0; fn < 4; fn++){
      const int h = wn + fn*16 + l15;
      #pragma unroll
      for (int r = 0; r < 4; r++){
        const int m = fm*16 + 4*q + r;
        if (m < nt){
          const float a1 = acc1[fm][fn][r];
          const float a3 = acc3[fm][fn][r];
          hrout[(size_t)(b0+m)*HE + h] = f2bf(a1 * sig_(a1) * a3 * tw[m]);
        }
      }
    }
  }
}

// ---------------------------------------------------------------------------
// Kernel 4: routed down (MFMA): out[tok][d] += hrout@W2[e] + tw*b2[e]
// BM=32, BN=512(full DM), K=256, BK=32. 4 waves: each owns 32x128.
// ---------------------------------------------------------------------------
__global__ __launch_bounds__(256) void k_down(
    const u16* __restrict__ hrout, const u16* __restrict__ W2bT,
    const float* __restrict__ b2,
    const int* __restrict__ bucket_tok, const float* __restrict__ bucket_w,
    const int* __restrict__ tiles, const int* __restrict__ n_tiles,
    float* __restrict__ out)
{
  if ((int)blockIdx.x >= *n_tiles) return;
  const int info = tiles[blockIdx.x];
  const int e  = info >> 20;
  const int b0 = (info >> 6) & 0x3FFF;
  const int nt = info & 63;

  __shared__ char As[32*64];
  __shared__ char Bs[512*64];
  __shared__ int   toks[32];
  __shared__ float tw[32];

  const int tid = threadIdx.x;
  const int wid = tid >> 6, lane = tid & 63;
  const int l15 = lane & 15, q = lane >> 4;
  const int wn = wid * 128;

  if (tid < 32){
    if (tid < nt){ toks[tid] = bucket_tok[b0+tid]; tw[tid] = bucket_w[b0+tid]; }
    else         { toks[tid] = 0; tw[tid] = 0.f; }
  }
  __syncthreads();

  f32x4 acc[2][8];
  #pragma unroll
  for (int fm = 0; fm < 2; fm++)
    #pragma unroll
    for (int fn = 0; fn < 8; fn++) acc[fm][fn] = (f32x4){0.f,0.f,0.f,0.f};

  const int arow = tid >> 3;
  const int ace  = (tid & 7) * 4;
  const u16* w2e = W2bT + (size_t)e*DM*HE;

  for (int ks = 0; ks < HE/32; ks++){
    const int k0 = ks*32;
    {
      uint2 v = *(const uint2*)(hrout + (size_t)(b0+arow)*HE + k0 + ace);
      *(uint2*)(As + arow*64 + ace*2) = v;
    }
    #pragma unroll
    for (int rr = 0; rr < 2; rr++){
      const int row = tid + rr*256;
      const u16* g = w2e + (size_t)row*HE + k0;
      #pragma unroll
      for (int j = 0; j < 4; j++)
        *(uint4*)(Bs + row*64 + j*16) = *(const uint4*)(g + j*8);
    }
    __syncthreads();
    bf16x8 fa0 = frd(As, 0  + l15, q);
    bf16x8 fa1 = frd(As, 16 + l15, q);
    #pragma unroll
    for (int fn = 0; fn < 8; fn++){
      bf16x8 fb = frd(Bs, wn + fn*16 + l15, q);
      acc[0][fn] = mfma16(fa0, fb, acc[0][fn]);
      acc[1][fn] = mfma16(fa1, fb, acc[1][fn]);
    }
    __syncthreads();
  }

  #pragma unroll
  for (int fm = 0; fm < 2; fm++){
    #pragma unroll
    for (int fn = 0; fn < 8; fn++){
      const int d = wn + fn*16 + l15;
      #pragma unroll
      for (int r = 0; r < 4; r++){
        const int m = fm*16 + 4*q + r;
        if (m < nt){
          atomicAdd(out + (size_t)toks[m]*DM + d, acc[fm][fn][r] + tw[m]*b2[(size_t)e*DM + d]);
        }
      }
    }
  }
}

// ---------------------------------------------------------------------------
// Kernel 5: shared up (MFMA): hbuf = swiglu(nx@Ws1p+bs1p, nx@Ws3p+bs3p)
// BM=64, BN=128, K=512, BK=32. 4 waves (2x2): each owns 32x64 per matrix.
// grid (TT/64, HSH/128)
// ---------------------------------------------------------------------------
__global__ __launch_bounds__(256) void k_shared_h(
    const u16* __restrict__ nxb,
    const u16* __restrict__ B1g, const u16* __restrict__ B3g,
    const float* __restrict__ bias1, const float* __restrict__ bias3,
    u16* __restrict__ hbuf)
{
  __shared__ char As[64*64];
  __shared__ char B1s[128*64];
  __shared__ char B3s[128*64];

  const int tid = threadIdx.x;
  const int t0 = blockIdx.x*64, h0 = blockIdx.y*128;
  const int wid = tid >> 6, lane = tid & 63;
  const int l15 = lane & 15, q = lane >> 4;
  const int wm = (wid & 1)*32, wn = (wid >> 1)*64;

  f32x4 acc1[2][4], acc3[2][4];
  #pragma unroll
  for (int fn = 0; fn < 4; fn++){
    const float b1v = bias1[h0 + wn + fn*16 + l15];
    const float b3v = bias3[h0 + wn + fn*16 + l15];
    #pragma unroll
    for (int fm = 0; fm < 2; fm++){
      acc1[fm][fn] = (f32x4){b1v,b1v,b1v,b1v};
      acc3[fm][fn] = (f32x4){b3v,b3v,b3v,b3v};
    }
  }

  const int ar = tid >> 2, acb = (tid & 3)*16;   // A: 64 rows, 16B chunk
  const int br = tid >> 1, bcb = (tid & 1)*32;   // B: 128 rows, 32B chunk

  for (int ks = 0; ks < DM/32; ks++){
    const int k0 = ks*32;
    {
      uint4 v = *(const uint4*)(nxb + (size_t)(t0+ar)*DM + k0 + acb/2);
      *(uint4*)(As + ar*64 + acb) = v;
    }
    {
      const u16* g1 = B1g + (size_t)(h0+br)*DM + k0 + bcb/2;
      const u16* g3 = B3g + (size_t)(h0+br)*DM + k0 + bcb/2;
      *(uint4*)(B1s + br*64 + bcb)      = *(const uint4*)(g1);
      *(uint4*)(B1s + br*64 + bcb + 16) = *(const uint4*)(g1 + 8);
      *(uint4*)(B3s + br*64 + bcb)      = *(const uint4*)(g3);
      *(uint4*)(B3s + br*64 + bcb + 16) = *(const uint4*)(g3 + 8);
    }
    __syncthreads();
    bf16x8 fa0 = frd(As, wm + 0  + l15, q);
    bf16x8 fa1 = frd(As, wm + 16 + l15, q);
    #pragma unroll
    for (int fn = 0; fn < 4; fn++){
      bf16x8 fb1 = frd(B1s, wn + fn*16 + l15, q);
      bf16x8 fb3 = frd(B3s, wn + fn*16 + l15, q);
      acc1[0][fn] = mfma16(fa0, fb1, acc1[0][fn]);
      acc1[1][fn] = mfma16(fa1, fb1, acc1[1][fn]);
      acc3[0][fn] = mfma16(fa0, fb3, acc3[0][fn]);
      acc3[1][fn] = mfma16(fa1, fb3, acc3[1][fn]);
    }
    __syncthreads();
  }

  #pragma unroll
  for (int fm = 0; fm < 2; fm++){
    #pragma unroll
    for (int fn = 0; fn < 4; fn++){
      const int h = h0 + wn + fn*16 + l15;
      const int tb = t0 + wm + fm*16 + 4*q;
      #pragma unroll
      for (int r = 0; r < 4; r++){
        const float a1 = acc1[fm][fn][r];
        const float a3 = acc3[fm][fn][r];
        hbuf[(size_t)(tb+r)*HSH + h] = f2bf(a1 * sig_(a1) * a3);
      }
    }
  }
}

// ---------------------------------------------------------------------------
// Kernel 6: shared down (MFMA): out[t][d] = hbuf@Ws2 + bs2  (direct write)
// BM=64, BN=128, K=2048, BK=32. grid (TT/64, DM/128)
// ---------------------------------------------------------------------------
__global__ __launch_bounds__(256) void k_shared_out(
    const u16* __restrict__ hbuf, const u16* __restrict__ Bg,
    const float* __restrict__ bs2, float* __restrict__ out)
{
  __shared__ char As[64*64];
  __shared__ char Bs[128*64];

  const int tid = threadIdx.x;
  const int t0 = blockIdx.x*64, d0 = blockIdx.y*128;
  const int wid = tid >> 6, lane = tid & 63;
  const int l15 = lane & 15, q = lane >> 4;
  const int wm = (wid & 1)*32, wn = (wid >> 1)*64;

  f32x4 acc[2][4];
  #pragma unroll
  for (int fm = 0; fm < 2; fm++)
    #pragma unroll
    for (int fn = 0; fn < 4; fn++) acc[fm][fn] = (f32x4){0.f,0.f,0.f,0.f};

  const int ar = tid >> 2, acb = (tid & 3)*16;
  const int br = tid >> 1, bcb = (tid & 1)*32;

  for (int ks = 0; ks < HSH/32; ks++){
    const int k0 = ks*32;
    {
      uint4 v = *(const uint4*)(hbuf + (size_t)(t0+ar)*HSH + k0 + acb/2);
      *(uint4*)(As + ar*64 + acb) = v;
    }
    {
      const u16* g = Bg + (size_t)(d0+br)*HSH + k0 + bcb/2;
      *(uint4*)(Bs + br*64 + bcb)      = *(const uint4*)(g);
      *(uint4*)(Bs + br*64 + bcb + 16) = *(const uint4*)(g + 8);
    }
    __syncthreads();
    bf16x8 fa0 = frd(As, wm + 0  + l15, q);
    bf16x8 fa1 = frd(As, wm + 16 + l15, q);
    #pragma unroll
    for (int fn = 0; fn < 4; fn++){
      bf16x8 fb = frd(Bs, wn + fn*16 + l15, q);
      acc[0][fn] = mfma16(fa0, fb, acc[0][fn]);
      acc[1][fn] = mfma16(fa1, fb, acc[1][fn]);
    }
    __syncthreads();
  }

  #pragma unroll
  for (int fm = 0; fm < 2; fm++){
    #pragma unroll
    for (int fn = 0; fn < 4; fn++){
      const int d = d0 + wn + fn*16 + l15;
      const int tb = t0 + wm + fm*16 + 4*q;
      const float bv = bs2[d];
      #pragma unroll
      for (int r = 0; r < 4; r++)
        out[(size_t)(tb+r)*DM + d] = acc[fm][fn][r] + bv;
    }
  }
}

// ---------------------------------------------------------------------------
extern "C" void kernel_launch(void* const* d_in, const int* in_sizes, int n_in,
                              void* d_out, int out_size, void* d_ws, size_t ws_size,
                              hipStream_t stream)
{
  (void)in_sizes; (void)n_in; (void)ws_size; (void)out_size;
  const float* x     = (const float*)d_in[0];
  const float* Wg    = (const float*)d_in[1];
  const float* bg    = (const float*)d_in[2];
  const float* gamma = (const float*)d_in[3];
  const float* beta  = (const float*)d_in[4];
  const float* W1    = (const float*)d_in[5];
  const float* b1    = (const float*)d_in[6];
  const float* W3    = (const float*)d_in[7];
  const float* b3    = (const float*)d_in[8];
  const float* W2    = (const float*)d_in[9];
  const float* b2    = (const float*)d_in[10];
  const float* gs    = (const float*)d_in[11];
  const float* bs    = (const float*)d_in[12];
  const float* Ws1   = (const float*)d_in[13];
  const float* bs1   = (const float*)d_in[14];
  const float* Ws3   = (const float*)d_in[15];
  const float* bs3   = (const float*)d_in[16];
  const float* Ws2   = (const float*)d_in[17];
  const float* bs2   = (const float*)d_in[18];
  float* out = (float*)d_out;

  char* ws = (char*)d_ws;
  size_t off = 0;
  auto alloc = [&](size_t bytes) -> char* {
    char* p = ws + off;
    off += (bytes + 255) & ~(size_t)255;
    return p;
  };
  u16*   nxb        = (u16*)  alloc((size_t)TT*DM*2);
  int*   top_idx    = (int*)  alloc((size_t)TT*2*4);
  float* top_w      = (float*)alloc((size_t)TT*2*4);
  int*   bucket_tok = (int*)  alloc((size_t)TT*2*4);
  float* bucket_w   = (float*)alloc((size_t)TT*2*4);
  int*   tiles      = (int*)  alloc(MAXTILES*4);
  int*   n_tiles    = (int*)  alloc(64);
  u16*   hrout      = (u16*)  alloc(((size_t)TT*2 + 32)*HE*2);
  u16*   hbuf       = (u16*)  alloc((size_t)TT*HSH*2);
  u16*   W1bT       = (u16*)  alloc((size_t)NE*HE*DM*2);
  u16*   W3bT       = (u16*)  alloc((size_t)NE*HE*DM*2);
  u16*   W2bT       = (u16*)  alloc((size_t)NE*DM*HE*2);
  u16*   Ws1bT      = (u16*)  alloc((size_t)HSH*DM*2);
  u16*   Ws3bT      = (u16*)  alloc((size_t)HSH*DM*2);
  u16*   Ws2bT      = (u16*)  alloc((size_t)DM*HSH*2);
  float* b1p        = (float*)alloc((size_t)NE*HE*4);
  float* b3p        = (float*)alloc((size_t)NE*HE*4);
  float* bs1p       = (float*)alloc(HSH*4);
  float* bs3p       = (float*)alloc(HSH*4);

  // --- pre-pass: weight convert/transpose + bias folds ---
  hipMemsetAsync(bs1p, 0, HSH*4, stream);
  hipMemsetAsync(bs3p, 0, HSH*4, stream);
  k_cvtT<<<dim3(DM/64, HE/64, NE), 256, 0, stream>>>(W1, gamma, W1bT, DM, HE);
  k_cvtT<<<dim3(DM/64, HE/64, NE), 256, 0, stream>>>(W3, gamma, W3bT, DM, HE);
  k_cvtT<<<dim3(HE/64, DM/64, NE), 256, 0, stream>>>(W2, nullptr, W2bT, HE, DM);
  k_cvtT<<<dim3(DM/64, HSH/64, 1), 256, 0, stream>>>(Ws1, gs, Ws1bT, DM, HSH);
  k_cvtT<<<dim3(DM/64, HSH/64, 1), 256, 0, stream>>>(Ws3, gs, Ws3bT, DM, HSH);
  k_cvtT<<<dim3(HSH/64, DM/64, 1), 256, 0, stream>>>(Ws2, nullptr, Ws2bT, HSH, DM);
  k_fold_rout<<<dim3(NE, 2), 256, 0, stream>>>(W1, W3, b1, b3, beta, b1p, b3p);
  k_fold_shared<<<dim3(8, 2), 256, 0, stream>>>(Ws1, Ws3, bs1, bs3, bs, bs1p, bs3p);

  // --- gate / routing ---
  k_ln_gate<<<dim3(TT), 256, 0, stream>>>(x, Wg, bg, nxb, top_idx, top_w);
  k_route<<<dim3(1), 256, 0, stream>>>(top_idx, top_w, bucket_tok, bucket_w, tiles, n_tiles);

  // --- expert GEMMs ---
  k_up<<<dim3(MAXTILES), 256, 0, stream>>>(nxb, W1bT, W3bT, b1p, b3p,
                                           bucket_tok, bucket_w, tiles, n_tiles, hrout);
  k_shared_h<<<dim3(TT/64, HSH/128), 256, 0, stream>>>(nxb, Ws1bT, Ws3bT, bs1p, bs3p, hbuf);
  k_shared_out<<<dim3(TT/64, DM/128), 256, 0, stream>>>(hbuf, Ws2bT, bs2, out);
  k_down<<<dim3(MAXTILES), 256, 0, stream>>>(hrout, W2bT, b2,
                                             bucket_tok, bucket_w, tiles, n_tiles, out);
}

// Round 4
// 287.164 us; speedup vs baseline: 9.6434x; 1.2692x over previous
//
#include <hip/hip_runtime.h>
#include <math.h>

typedef unsigned short u16;
typedef __attribute__((ext_vector_type(8))) short bf16x8;
typedef __attribute__((ext_vector_type(4))) float f32x4;

#define TT   4096   // tokens
#define DM   512    // model dim
#define NE   64     // routed experts
#define HE   256    // expert hidden (also pseudo-expert slice of shared)
#define HSH  2048   // shared expert hidden = 8 * 256
#define NSH  8      // shared pseudo-experts
#define PADBASE 16384          // hrout base for shared slots
#define MAXTILES 384           // <=128 routed (M=128) + 256 shared

__device__ __forceinline__ float sig_(float z){ return 1.f/(1.f+__expf(-z)); }

__device__ __forceinline__ u16 f2bf(float x){
  unsigned int u = __builtin_bit_cast(unsigned int, x);
  u = (u + 0x7FFFu + ((u >> 16) & 1u)) >> 16;
  return (u16)u;
}

__device__ __forceinline__ f32x4 mfma16(bf16x8 a, bf16x8 b, f32x4 c){
  return __builtin_amdgcn_mfma_f32_16x16x32_bf16(a, b, c, 0, 0, 0);
}

// fragment read: row-major [rows][32k] tile, 64B rows
__device__ __forceinline__ bf16x8 frd(const char* tile, int row, int q){
  return *(const bf16x8*)(tile + row*64 + q*16);
}

// async global->LDS, 16B per lane; lds dest = base + lane*16 (wave-linear)
__device__ __forceinline__ void gl16(const void* g, void* l){
  __builtin_amdgcn_global_load_lds(
      (const __attribute__((address_space(1))) unsigned int*)g,
      (__attribute__((address_space(3))) unsigned int*)l, 16, 0, 0);
}

// ---------------------------------------------------------------------------
// Pre-pass: transpose-convert fp32 [K][N] -> bf16 [N][K] with optional row
// scale (LN gamma folded into W), FUSED bias fold: foldout[n] += sum_k fv[k]*W[k][n].
// grid (K/64, N/64, nmat)
// ---------------------------------------------------------------------------
__global__ __launch_bounds__(256) void k_cvtT(
    const float* __restrict__ in, const float* __restrict__ scale,
    const float* __restrict__ foldvec, u16* __restrict__ out,
    float* __restrict__ foldout, int K, int N)
{
  __shared__ u16 T[64][80];
  __shared__ float red[64][65];
  const int tid = threadIdx.x;
  const int k0 = blockIdx.x*64, n0 = blockIdx.y*64;
  const float* ip = in + (size_t)blockIdx.z * K * N;
  const int r = tid>>2, cb = (tid&3)*16;
  const float sc = scale   ? scale[(size_t)blockIdx.z*K + k0 + r]   : 1.0f;
  const float fv = foldvec ? foldvec[(size_t)blockIdx.z*K + k0 + r] : 0.0f;
  #pragma unroll
  for (int j = 0; j < 4; j++){
    float4 v = *(const float4*)(ip + (size_t)(k0+r)*N + n0 + cb + j*4);
    T[cb+j*4+0][r] = f2bf(v.x*sc);
    T[cb+j*4+1][r] = f2bf(v.y*sc);
    T[cb+j*4+2][r] = f2bf(v.z*sc);
    T[cb+j*4+3][r] = f2bf(v.w*sc);
    if (foldout){
      red[cb+j*4+0][r] = v.x*fv;
      red[cb+j*4+1][r] = v.y*fv;
      red[cb+j*4+2][r] = v.z*fv;
      red[cb+j*4+3][r] = v.w*fv;
    }
  }
  __syncthreads();
  if (foldout){
    const int c = tid & 63, rq = tid >> 6;
    float s = 0.f;
    #pragma unroll
    for (int rr = 0; rr < 16; rr++) s += red[c][rq*16 + rr];
    atomicAdd(foldout + (size_t)blockIdx.z*N + n0 + c, s);
  }
  const int n = tid>>2, kb = (tid&3)*16;
  uint4 a = *(const uint4*)&T[n][kb];
  uint4 b = *(const uint4*)&T[n][kb+8];
  u16* op = out + (size_t)blockIdx.z*K*N;
  *(uint4*)(op + (size_t)(n0+n)*K + k0 + kb)     = a;
  *(uint4*)(op + (size_t)(n0+n)*K + k0 + kb + 8) = b;
}

// ---------------------------------------------------------------------------
// Kernel 1: per-token LN stats -> nxb (bf16), gate logits + top-2.
// ---------------------------------------------------------------------------
__global__ __launch_bounds__(256) void k_ln_gate(
    const float* __restrict__ x, const float* __restrict__ Wg, const float* __restrict__ bg,
    u16* __restrict__ nxb, int* __restrict__ top_idx, float* __restrict__ top_w)
{
  __shared__ float xs[DM];
  __shared__ float sred[4], ssred[4];
  __shared__ float sc[NE];
  const int tid = threadIdx.x;
  const int t   = blockIdx.x;

  float2 v = reinterpret_cast<const float2*>(x + (size_t)t*DM)[tid];
  xs[2*tid]   = v.x;
  xs[2*tid+1] = v.y;
  float s  = v.x + v.y;
  float ss = v.x*v.x + v.y*v.y;
  #pragma unroll
  for (int o = 32; o > 0; o >>= 1){ s += __shfl_xor(s, o); ss += __shfl_xor(ss, o); }
  const int wid = tid >> 6, lane = tid & 63;
  if (lane == 0){ sred[wid] = s; ssred[wid] = ss; }
  __syncthreads();
  const float tot = sred[0]+sred[1]+sred[2]+sred[3];
  const float tss = ssred[0]+ssred[1]+ssred[2]+ssred[3];
  const float mu  = tot * (1.f/DM);
  const float var = tss * (1.f/DM) - mu*mu;
  const float rstd = rsqrtf(var + 1e-5f);
  unsigned int pk = (unsigned int)f2bf((v.x-mu)*rstd) | ((unsigned int)f2bf((v.y-mu)*rstd) << 16);
  *(unsigned int*)(nxb + (size_t)t*DM + 2*tid) = pk;

  const int e = tid >> 2, sub = tid & 3;
  const float4* wrow4 = reinterpret_cast<const float4*>(Wg + (size_t)e*DM);
  const float4* xs4   = reinterpret_cast<const float4*>(xs);
  float acc = 0.f;
  #pragma unroll 4
  for (int i = sub; i < DM/4; i += 4){
    const float4 w = wrow4[i]; const float4 xv = xs4[i];
    acc += xv.x*w.x + xv.y*w.y + xv.z*w.z + xv.w*w.w;
  }
  acc += __shfl_xor(acc, 1);
  acc += __shfl_xor(acc, 2);
  if (sub == 0) sc[e] = acc + bg[e];
  __syncthreads();

  if (tid < 64) {
    const float s0 = sc[tid];
    float m = s0; int mi = tid;
    #pragma unroll
    for (int o = 1; o < 64; o <<= 1){
      float om = __shfl_xor(m, o); int oi = __shfl_xor(mi, o);
      if (om > m || (om == m && oi < mi)) { m = om; mi = oi; }
    }
    float s1 = (tid == mi) ? -INFINITY : s0;
    float m2 = s1; int mi2 = tid;
    #pragma unroll
    for (int o = 1; o < 64; o <<= 1){
      float om = __shfl_xor(m2, o); int oi = __shfl_xor(mi2, o);
      if (om > m2 || (om == m2 && oi < mi2)) { m2 = om; mi2 = oi; }
    }
    if (tid == 0){
      const float w0 = sig_(m), w1 = sig_(m2);
      const float inv = 1.f/(w0+w1);
      top_idx[2*t]   = mi;
      top_idx[2*t+1] = mi2;
      top_w[2*t]     = w0*inv;
      top_w[2*t+1]   = w1*inv;
    }
  }
}

// ---------------------------------------------------------------------------
// Kernel 2: routing. Padded (M=128) per-expert bases, scatter, tile list.
// Tile info: e[7b] << 17 | (b0>>7)[9b] << 8 | nt[8b].
// Shared pseudo-experts appended: e = 64+s, b0 = PADBASE + s*4096 + t0.
// ---------------------------------------------------------------------------
__global__ __launch_bounds__(256) void k_route(
    const int* __restrict__ top_idx, const float* __restrict__ top_w,
    int* __restrict__ bucket_tok, float* __restrict__ bucket_w,
    int* __restrict__ tiles, int* __restrict__ n_tiles)
{
  __shared__ int cnt[NE], base_[NE];
  __shared__ int nroute;
  const int tid = threadIdx.x;
  if (tid < NE) cnt[tid] = 0;
  __syncthreads();
  for (int p = tid; p < TT*2; p += 256) atomicAdd(&cnt[top_idx[p]], 1);
  __syncthreads();
  if (tid == 0){
    int run = 0, ntl = 0;
    for (int e = 0; e < NE; e++){
      base_[e] = run;
      const int c = cnt[e];
      for (int b = 0; b < c; b += 128){
        const int n = (c - b < 128) ? (c - b) : 128;
        tiles[ntl++] = (e << 17) | (((run + b) >> 7) << 8) | n;
      }
      run += ((c + 127) >> 7) << 7;   // padded advance
    }
    nroute = ntl;
    *n_tiles = ntl + NSH*(TT/128);
  }
  __syncthreads();
  // shared tiles (parallel emit)
  if (tid < NSH*(TT/128)){
    const int s = tid >> 5, t = tid & 31;     // TT/128 = 32
    const int b0 = PADBASE + s*TT + t*128;
    tiles[nroute + tid] = ((NE + s) << 17) | ((b0 >> 7) << 8) | 128;
  }
  if (tid < NE) cnt[tid] = 0;
  __syncthreads();
  for (int p = tid; p < TT*2; p += 256){
    const int e = top_idx[p];
    const int pos = base_[e] + atomicAdd(&cnt[e], 1);
    bucket_tok[pos] = p >> 1;
    bucket_w[pos]   = top_w[p];
  }
}

// ---------------------------------------------------------------------------
// Kernel 3: unified up-proj. M=128, BN=256, K=512, BK=32, dbuf + gload_lds.
// 512 threads, 8 waves (2M x 4N). hrout[slot][h] = swiglu(...)*tw (0 for pad).
// ---------------------------------------------------------------------------
__global__ __launch_bounds__(512) void k_up(
    const u16* __restrict__ nxb,
    const u16* __restrict__ W1bT, const u16* __restrict__ W3bT,
    const u16* __restrict__ Ws1bT, const u16* __restrict__ Ws3bT,
    const float* __restrict__ b1, const float* __restrict__ b3,
    const float* __restrict__ bs1, const float* __restrict__ bs3,
    const float* __restrict__ b1f, const float* __restrict__ b3f,
    const int* __restrict__ bucket_tok, const float* __restrict__ bucket_w,
    const int* __restrict__ tiles, const int* __restrict__ n_tiles,
    u16* __restrict__ hrout)
{
  if ((int)blockIdx.x >= *n_tiles) return;
  const int info = tiles[blockIdx.x];
  const int e  = info >> 17;
  const int b0 = ((info >> 8) & 0x1FF) << 7;
  const int nt = info & 255;
  const bool sh = (e >= NE);

  __shared__ __align__(16) char Ab[2][8192];     // 128 x 32k bf16
  __shared__ __align__(16) char B1b[2][16384];   // 256 x 32k
  __shared__ __align__(16) char B3b[2][16384];
  __shared__ int   toks[128];
  __shared__ float tw[128];

  const int tid = threadIdx.x, wid = tid >> 6, lane = tid & 63;
  const int l15 = lane & 15, q = lane >> 4;

  if (tid < 128){
    int tk; float w;
    if (!sh){
      if (tid < nt){ tk = bucket_tok[b0+tid]; w = bucket_w[b0+tid]; }
      else         { tk = 0; w = 0.f; }
    } else {
      tk = ((b0 - PADBASE) & (TT-1)) + tid; w = 1.f;
    }
    toks[tid] = tk; tw[tid] = w;
  }
  __syncthreads();

  const u16* w1e = sh ? (Ws1bT + (size_t)(e-NE)*HE*DM) : (W1bT + (size_t)e*HE*DM);
  const u16* w3e = sh ? (Ws3bT + (size_t)(e-NE)*HE*DM) : (W3bT + (size_t)e*HE*DM);

  const int l2 = lane >> 2, l3e = (lane & 3)*8;
  const u16* asrc = nxb + (size_t)toks[wid*16 + l2]*DM + l3e;
  const u16* b1s0 = w1e + (size_t)(wid*32 + l2)*DM + l3e;
  const u16* b1s1 = b1s0 + (size_t)16*DM;
  const u16* b3s0 = w3e + (size_t)(wid*32 + l2)*DM + l3e;
  const u16* b3s1 = b3s0 + (size_t)16*DM;
  const int aoff = wid*1024, boff = wid*2048;

#define UP_STAGE(ph, k0) do{ \
    gl16(asrc + (k0), Ab[ph] + aoff); \
    gl16(b1s0 + (k0), B1b[ph] + boff); \
    gl16(b1s1 + (k0), B1b[ph] + boff + 1024); \
    gl16(b3s0 + (k0), B3b[ph] + boff); \
    gl16(b3s1 + (k0), B3b[ph] + boff + 1024); \
  } while(0)

  const int wm = (wid & 1)*64, wn = (wid >> 1)*64;

  const float* ob1 = sh ? (bs1 + (size_t)(e-NE)*HE) : (b1 + (size_t)e*HE);
  const float* ob3 = sh ? (bs3 + (size_t)(e-NE)*HE) : (b3 + (size_t)e*HE);
  f32x4 acc1[4][4], acc3[4][4];
  #pragma unroll
  for (int fn = 0; fn < 4; fn++){
    const int h = wn + fn*16 + l15;
    const float v1 = ob1[h] + b1f[(size_t)e*HE + h];   // concat fold layout
    const float v3 = ob3[h] + b3f[(size_t)e*HE + h];
    #pragma unroll
    for (int fm = 0; fm < 4; fm++){
      acc1[fm][fn] = (f32x4){v1,v1,v1,v1};
      acc3[fm][fn] = (f32x4){v3,v3,v3,v3};
    }
  }

  UP_STAGE(0, 0);
  __syncthreads();

  for (int ks = 0; ks < DM/32; ks++){
    const int cur = ks & 1;
    if (ks < DM/32 - 1) UP_STAGE(cur^1, (ks+1)*32);
    const char* A  = Ab[cur];
    const char* B1 = B1b[cur];
    const char* B3 = B3b[cur];
    bf16x8 fa[4];
    #pragma unroll
    for (int fm = 0; fm < 4; fm++) fa[fm] = frd(A, wm + fm*16 + l15, q);
    #pragma unroll
    for (int fn = 0; fn < 4; fn++){
      bf16x8 fb1 = frd(B1, wn + fn*16 + l15, q);
      bf16x8 fb3 = frd(B3, wn + fn*16 + l15, q);
      #pragma unroll
      for (int fm = 0; fm < 4; fm++){
        acc1[fm][fn] = mfma16(fa[fm], fb1, acc1[fm][fn]);
        acc3[fm][fn] = mfma16(fa[fm], fb3, acc3[fm][fn]);
      }
    }
    __syncthreads();
  }
#undef UP_STAGE

  #pragma unroll
  for (int fm = 0; fm < 4; fm++){
    #pragma unroll
    for (int fn = 0; fn < 4; fn++){
      const int h = wn + fn*16 + l15;
      #pragma unroll
      for (int r = 0; r < 4; r++){
        const int m = wm + fm*16 + 4*q + r;
        float v = 0.f;
        if (m < nt){
          const float a1 = acc1[fm][fn][r];
          const float a3 = acc3[fm][fn][r];
          v = a1 * sig_(a1) * a3 * tw[m];
        }
        hrout[(size_t)(b0+m)*HE + h] = f2bf(v);
      }
    }
  }
}

// ---------------------------------------------------------------------------
// Kernel 4: unified down-proj. M=128, BN=512(DM), K=256, BK=32, dbuf+gload_lds.
// 512 threads, 8 waves (2M x 4N). atomicAdd into out.
// ---------------------------------------------------------------------------
__global__ __launch_bounds__(512) void k_down(
    const u16* __restrict__ hrout,
    const u16* __restrict__ W2bT, const u16* __restrict__ Ws2bT,
    const float* __restrict__ b2, const float* __restrict__ bs2,
    const int* __restrict__ bucket_tok, const float* __restrict__ bucket_w,
    const int* __restrict__ tiles, const int* __restrict__ n_tiles,
    float* __restrict__ out)
{
  if ((int)blockIdx.x >= *n_tiles) return;
  const int info = tiles[blockIdx.x];
  const int e  = info >> 17;
  const int b0 = ((info >> 8) & 0x1FF) << 7;
  const int nt = info & 255;
  const bool sh = (e >= NE);

  __shared__ __align__(16) char Ab[2][8192];     // 128 x 32k
  __shared__ __align__(16) char Bb[2][32768];    // 512 x 32k
  __shared__ int   toks[128];
  __shared__ float tw[128];

  const int tid = threadIdx.x, wid = tid >> 6, lane = tid & 63;
  const int l15 = lane & 15, q = lane >> 4;

  if (tid < 128){
    int tk; float w;
    if (!sh){
      if (tid < nt){ tk = bucket_tok[b0+tid]; w = bucket_w[b0+tid]; }
      else         { tk = 0; w = 0.f; }
    } else {
      tk = ((b0 - PADBASE) & (TT-1)) + tid; w = 1.f;
    }
    toks[tid] = tk; tw[tid] = w;
  }
  __syncthreads();

  const u16* w2e; size_t ldb;
  if (sh){ w2e = Ws2bT + (size_t)(e-NE)*HE; ldb = HSH; }
  else   { w2e = W2bT + (size_t)e*DM*HE;    ldb = HE;  }

  const int l2 = lane >> 2, l3e = (lane & 3)*8;
  const u16* asrc  = hrout + (size_t)(b0 + wid*16 + l2)*HE + l3e;
  const u16* bsrc0 = w2e + (size_t)(wid*64 +  0 + l2)*ldb + l3e;
  const u16* bsrc1 = w2e + (size_t)(wid*64 + 16 + l2)*ldb + l3e;
  const u16* bsrc2 = w2e + (size_t)(wid*64 + 32 + l2)*ldb + l3e;
  const u16* bsrc3 = w2e + (size_t)(wid*64 + 48 + l2)*ldb + l3e;
  const int aoff = wid*1024, boff = wid*4096;

#define DN_STAGE(ph, k0) do{ \
    gl16(asrc  + (k0), Ab[ph] + aoff); \
    gl16(bsrc0 + (k0), Bb[ph] + boff); \
    gl16(bsrc1 + (k0), Bb[ph] + boff + 1024); \
    gl16(bsrc2 + (k0), Bb[ph] + boff + 2048); \
    gl16(bsrc3 + (k0), Bb[ph] + boff + 3072); \
  } while(0)

  const int wm = (wid & 1)*64, wn = (wid >> 1)*128;

  f32x4 acc[4][8];
  #pragma unroll
  for (int fm = 0; fm < 4; fm++)
    #pragma unroll
    for (int fn = 0; fn < 8; fn++) acc[fm][fn] = (f32x4){0.f,0.f,0.f,0.f};

  DN_STAGE(0, 0);
  __syncthreads();

  for (int ks = 0; ks < HE/32; ks++){
    const int cur = ks & 1;
    if (ks < HE/32 - 1) DN_STAGE(cur^1, (ks+1)*32);
    const char* A = Ab[cur];
    const char* B = Bb[cur];
    bf16x8 fa[4];
    #pragma unroll
    for (int fm = 0; fm < 4; fm++) fa[fm] = frd(A, wm + fm*16 + l15, q);
    #pragma unroll
    for (int fn = 0; fn < 8; fn++){
      bf16x8 fb = frd(B, wn + fn*16 + l15, q);
      #pragma unroll
      for (int fm = 0; fm < 4; fm++)
        acc[fm][fn] = mfma16(fa[fm], fb, acc[fm][fn]);
    }
    __syncthreads();
  }
#undef DN_STAGE

  #pragma unroll
  for (int fm = 0; fm < 4; fm++){
    #pragma unroll
    for (int fn = 0; fn < 8; fn++){
      const int d = wn + fn*16 + l15;
      #pragma unroll
      for (int r = 0; r < 4; r++){
        const int m = wm + fm*16 + 4*q + r;
        if (m < nt){
          float badd;
          if (sh) badd = (e == NE) ? bs2[d] : 0.f;
          else    badd = tw[m] * b2[(size_t)e*DM + d];
          atomicAdd(out + (size_t)toks[m]*DM + d, acc[fm][fn][r] + badd);
        }
      }
    }
  }
}

// ---------------------------------------------------------------------------
extern "C" void kernel_launch(void* const* d_in, const int* in_sizes, int n_in,
                              void* d_out, int out_size, void* d_ws, size_t ws_size,
                              hipStream_t stream)
{
  (void)in_sizes; (void)n_in; (void)ws_size;
  const float* x     = (const float*)d_in[0];
  const float* Wg    = (const float*)d_in[1];
  const float* bg    = (const float*)d_in[2];
  const float* gamma = (const float*)d_in[3];
  const float* beta  = (const float*)d_in[4];
  const float* W1    = (const float*)d_in[5];
  const float* b1    = (const float*)d_in[6];
  const float* W3    = (const float*)d_in[7];
  const float* b3    = (const float*)d_in[8];
  const float* W2    = (const float*)d_in[9];
  const float* b2    = (const float*)d_in[10];
  const float* gs    = (const float*)d_in[11];
  const float* bs    = (const float*)d_in[12];
  const float* Ws1   = (const float*)d_in[13];
  const float* bs1   = (const float*)d_in[14];
  const float* Ws3   = (const float*)d_in[15];
  const float* bs3   = (const float*)d_in[16];
  const float* Ws2   = (const float*)d_in[17];
  const float* bs2   = (const float*)d_in[18];
  float* out = (float*)d_out;

  char* ws = (char*)d_ws;
  size_t off = 0;
  auto alloc = [&](size_t bytes) -> char* {
    char* p = ws + off;
    off += (bytes + 255) & ~(size_t)255;
    return p;
  };
  u16*   nxb        = (u16*)  alloc((size_t)TT*DM*2);
  int*   top_idx    = (int*)  alloc((size_t)TT*2*4);
  float* top_w      = (float*)alloc((size_t)TT*2*4);
  int*   bucket_tok = (int*)  alloc((size_t)PADBASE*4);
  float* bucket_w   = (float*)alloc((size_t)PADBASE*4);
  int*   tiles      = (int*)  alloc(MAXTILES*4);
  int*   n_tiles    = (int*)  alloc(64);
  u16*   hrout      = (u16*)  alloc((size_t)(PADBASE + NSH*TT)*HE*2);   // 25.2 MB
  u16*   W1bT       = (u16*)  alloc((size_t)NE*HE*DM*2);
  u16*   W3bT       = (u16*)  alloc((size_t)NE*HE*DM*2);
  u16*   W2bT       = (u16*)  alloc((size_t)NE*DM*HE*2);
  u16*   Ws1bT      = (u16*)  alloc((size_t)HSH*DM*2);
  u16*   Ws3bT      = (u16*)  alloc((size_t)HSH*DM*2);
  u16*   Ws2bT      = (u16*)  alloc((size_t)DM*HSH*2);
  float* b1f        = (float*)alloc((size_t)(NE*HE + HSH)*4);   // routed fold ++ shared fold
  float* b3f        = (float*)alloc((size_t)(NE*HE + HSH)*4);

  // --- pre-pass: convert/transpose weights, fused bias folds ---
  hipMemsetAsync(b1f, 0, (size_t)(NE*HE + HSH)*4, stream);
  hipMemsetAsync(b3f, 0, (size_t)(NE*HE + HSH)*4, stream);
  hipMemsetAsync(out, 0, (size_t)out_size*sizeof(float), stream);
  k_cvtT<<<dim3(DM/64, HE/64, NE), 256, 0, stream>>>(W1, gamma, beta, W1bT, b1f, DM, HE);
  k_cvtT<<<dim3(DM/64, HE/64, NE), 256, 0, stream>>>(W3, gamma, beta, W3bT, b3f, DM, HE);
  k_cvtT<<<dim3(HE/64, DM/64, NE), 256, 0, stream>>>(W2, nullptr, nullptr, W2bT, nullptr, HE, DM);
  k_cvtT<<<dim3(DM/64, HSH/64, 1), 256, 0, stream>>>(Ws1, gs, bs, Ws1bT, b1f + NE*HE, DM, HSH);
  k_cvtT<<<dim3(DM/64, HSH/64, 1), 256, 0, stream>>>(Ws3, gs, bs, Ws3bT, b3f + NE*HE, DM, HSH);
  k_cvtT<<<dim3(HSH/64, DM/64, 1), 256, 0, stream>>>(Ws2, nullptr, nullptr, Ws2bT, nullptr, HSH, DM);

  // --- gate / routing ---
  k_ln_gate<<<dim3(TT), 256, 0, stream>>>(x, Wg, bg, nxb, top_idx, top_w);
  k_route<<<dim3(1), 256, 0, stream>>>(top_idx, top_w, bucket_tok, bucket_w, tiles, n_tiles);

  // --- unified expert GEMMs (routed + shared pseudo-experts) ---
  k_up<<<dim3(MAXTILES), 512, 0, stream>>>(nxb, W1bT, W3bT, Ws1bT, Ws3bT,
                                           b1, b3, bs1, bs3, b1f, b3f,
                                           bucket_tok, bucket_w, tiles, n_tiles, hrout);
  k_down<<<dim3(MAXTILES), 512, 0, stream>>>(hrout, W2bT, Ws2bT, b2, bs2,
                                             bucket_tok, bucket_w, tiles, n_tiles, out);
}

// Round 5
// 226.062 us; speedup vs baseline: 12.2499x; 1.2703x over previous
//
#include <hip/hip_runtime.h>
#include <math.h>

typedef unsigned short u16;
typedef __attribute__((ext_vector_type(8))) short bf16x8;
typedef __attribute__((ext_vector_type(4))) float f32x4;

#define TT   4096   // tokens
#define DM   512    // model dim
#define NE   64     // routed experts
#define HE   256    // expert hidden (also pseudo-expert slice of shared)
#define HSH  2048   // shared expert hidden = 8 * 256
#define NSH  8      // shared pseudo-experts
#define PADBASE 16384          // shared tile b0 encoding base
#define MAXTILES 384           // <=128 routed (M=128) + 256 shared
#define MAXRT    128           // max routed tiles

__device__ __forceinline__ float sig_(float z){ return 1.f/(1.f+__expf(-z)); }

__device__ __forceinline__ u16 f2bf(float x){
  unsigned int u = __builtin_bit_cast(unsigned int, x);
  u = (u + 0x7FFFu + ((u >> 16) & 1u)) >> 16;
  return (u16)u;
}

__device__ __forceinline__ f32x4 mfma16(bf16x8 a, bf16x8 b, f32x4 c){
  return __builtin_amdgcn_mfma_f32_16x16x32_bf16(a, b, c, 0, 0, 0);
}

// fragment read: row-major [rows][32k] tile, 64B rows
__device__ __forceinline__ bf16x8 frd(const char* tile, int row, int q){
  return *(const bf16x8*)(tile + row*64 + q*16);
}

// async global->LDS, 16B per lane; lds dest = wave base + lane*16 (wave-linear)
__device__ __forceinline__ void gl16(const void* g, void* l){
  __builtin_amdgcn_global_load_lds(
      (const __attribute__((address_space(1))) unsigned int*)g,
      (__attribute__((address_space(3))) unsigned int*)l, 16, 0, 0);
}

// ---------------------------------------------------------------------------
// Pre-pass: transpose-convert fp32 [K][N] -> bf16 [N][K] with optional row
// scale (LN gamma) and fused bias fold: foldout[n] += sum_k fv[k]*W[k][n].
// grid (K/64, N/64, nmat)
// ---------------------------------------------------------------------------
__global__ __launch_bounds__(256) void k_cvtT(
    const float* __restrict__ in, const float* __restrict__ scale,
    const float* __restrict__ foldvec, u16* __restrict__ out,
    float* __restrict__ foldout, int K, int N)
{
  __shared__ u16 T[64][80];
  __shared__ float red[64][65];
  const int tid = threadIdx.x;
  const int k0 = blockIdx.x*64, n0 = blockIdx.y*64;
  const float* ip = in + (size_t)blockIdx.z * K * N;
  const int r = tid>>2, cb = (tid&3)*16;
  const float sc = scale   ? scale[(size_t)blockIdx.z*K + k0 + r]   : 1.0f;
  const float fv = foldvec ? foldvec[(size_t)blockIdx.z*K + k0 + r] : 0.0f;
  #pragma unroll
  for (int j = 0; j < 4; j++){
    float4 v = *(const float4*)(ip + (size_t)(k0+r)*N + n0 + cb + j*4);
    T[cb+j*4+0][r] = f2bf(v.x*sc);
    T[cb+j*4+1][r] = f2bf(v.y*sc);
    T[cb+j*4+2][r] = f2bf(v.z*sc);
    T[cb+j*4+3][r] = f2bf(v.w*sc);
    if (foldout){
      red[cb+j*4+0][r] = v.x*fv;
      red[cb+j*4+1][r] = v.y*fv;
      red[cb+j*4+2][r] = v.z*fv;
      red[cb+j*4+3][r] = v.w*fv;
    }
  }
  __syncthreads();
  if (foldout){
    const int c = tid & 63, rq = tid >> 6;
    float s = 0.f;
    #pragma unroll
    for (int rr = 0; rr < 16; rr++) s += red[c][rq*16 + rr];
    atomicAdd(foldout + (size_t)blockIdx.z*N + n0 + c, s);
  }
  const int n = tid>>2, kb = (tid&3)*16;
  uint4 a = *(const uint4*)&T[n][kb];
  uint4 b = *(const uint4*)&T[n][kb+8];
  u16* op = out + (size_t)blockIdx.z*K*N;
  *(uint4*)(op + (size_t)(n0+n)*K + k0 + kb)     = a;
  *(uint4*)(op + (size_t)(n0+n)*K + k0 + kb + 8) = b;
}

// ---------------------------------------------------------------------------
// Kernel 1: per-token LN stats -> nxb (bf16), gate logits + top-2.
// ---------------------------------------------------------------------------
__global__ __launch_bounds__(256) void k_ln_gate(
    const float* __restrict__ x, const float* __restrict__ Wg, const float* __restrict__ bg,
    u16* __restrict__ nxb, int* __restrict__ top_idx, float* __restrict__ top_w)
{
  __shared__ float xs[DM];
  __shared__ float sred[4], ssred[4];
  __shared__ float sc[NE];
  const int tid = threadIdx.x;
  const int t   = blockIdx.x;

  float2 v = reinterpret_cast<const float2*>(x + (size_t)t*DM)[tid];
  xs[2*tid]   = v.x;
  xs[2*tid+1] = v.y;
  float s  = v.x + v.y;
  float ss = v.x*v.x + v.y*v.y;
  #pragma unroll
  for (int o = 32; o > 0; o >>= 1){ s += __shfl_xor(s, o); ss += __shfl_xor(ss, o); }
  const int wid = tid >> 6, lane = tid & 63;
  if (lane == 0){ sred[wid] = s; ssred[wid] = ss; }
  __syncthreads();
  const float tot = sred[0]+sred[1]+sred[2]+sred[3];
  const float tss = ssred[0]+ssred[1]+ssred[2]+ssred[3];
  const float mu  = tot * (1.f/DM);
  const float var = tss * (1.f/DM) - mu*mu;
  const float rstd = rsqrtf(var + 1e-5f);
  unsigned int pk = (unsigned int)f2bf((v.x-mu)*rstd) | ((unsigned int)f2bf((v.y-mu)*rstd) << 16);
  *(unsigned int*)(nxb + (size_t)t*DM + 2*tid) = pk;

  const int e = tid >> 2, sub = tid & 3;
  const float4* wrow4 = reinterpret_cast<const float4*>(Wg + (size_t)e*DM);
  const float4* xs4   = reinterpret_cast<const float4*>(xs);
  float acc = 0.f;
  #pragma unroll 4
  for (int i = sub; i < DM/4; i += 4){
    const float4 w = wrow4[i]; const float4 xv = xs4[i];
    acc += xv.x*w.x + xv.y*w.y + xv.z*w.z + xv.w*w.w;
  }
  acc += __shfl_xor(acc, 1);
  acc += __shfl_xor(acc, 2);
  if (sub == 0) sc[e] = acc + bg[e];
  __syncthreads();

  if (tid < 64) {
    const float s0 = sc[tid];
    float m = s0; int mi = tid;
    #pragma unroll
    for (int o = 1; o < 64; o <<= 1){
      float om = __shfl_xor(m, o); int oi = __shfl_xor(mi, o);
      if (om > m || (om == m && oi < mi)) { m = om; mi = oi; }
    }
    float s1 = (tid == mi) ? -INFINITY : s0;
    float m2 = s1; int mi2 = tid;
    #pragma unroll
    for (int o = 1; o < 64; o <<= 1){
      float om = __shfl_xor(m2, o); int oi = __shfl_xor(mi2, o);
      if (om > m2 || (om == m2 && oi < mi2)) { m2 = om; mi2 = oi; }
    }
    if (tid == 0){
      const float w0 = sig_(m), w1 = sig_(m2);
      const float inv = 1.f/(w0+w1);
      top_idx[2*t]   = mi;
      top_idx[2*t+1] = mi2;
      top_w[2*t]     = w0*inv;
      top_w[2*t+1]   = w1*inv;
    }
  }
}

// ---------------------------------------------------------------------------
// Kernel 2: routing. Padded (M=128) per-expert bases, scatter, tile list.
// Tile info: e[7b]<<17 | (b0>>7)[9b]<<8 | nt[8b].
// Shared pseudo tiles appended: e = 64+s, b0 = PADBASE + s*TT + t0.
// n_tiles[0] = total tiles, n_tiles[1] = routed tiles.
// ---------------------------------------------------------------------------
__global__ __launch_bounds__(256) void k_route(
    const int* __restrict__ top_idx, const float* __restrict__ top_w,
    int* __restrict__ bucket_tok, float* __restrict__ bucket_w,
    int* __restrict__ tiles, int* __restrict__ n_tiles)
{
  __shared__ int cnt[NE], base_[NE];
  __shared__ int nroute;
  const int tid = threadIdx.x;
  if (tid < NE) cnt[tid] = 0;
  __syncthreads();
  for (int p = tid; p < TT*2; p += 256) atomicAdd(&cnt[top_idx[p]], 1);
  __syncthreads();
  if (tid == 0){
    int run = 0, ntl = 0;
    for (int e = 0; e < NE; e++){
      base_[e] = run;
      const int c = cnt[e];
      for (int b = 0; b < c; b += 128){
        const int n = (c - b < 128) ? (c - b) : 128;
        tiles[ntl++] = (e << 17) | (((run + b) >> 7) << 8) | n;
      }
      run += ((c + 127) >> 7) << 7;   // padded advance
    }
    nroute = ntl;
    n_tiles[0] = ntl + NSH*(TT/128);
    n_tiles[1] = ntl;
  }
  __syncthreads();
  if (tid < NSH*(TT/128)){
    const int s = tid >> 5, t = tid & 31;     // TT/128 = 32
    const int b0 = PADBASE + s*TT + t*128;
    tiles[nroute + tid] = ((NE + s) << 17) | ((b0 >> 7) << 8) | 128;
  }
  if (tid < NE) cnt[tid] = 0;
  __syncthreads();
  for (int p = tid; p < TT*2; p += 256){
    const int e = top_idx[p];
    const int pos = base_[e] + atomicAdd(&cnt[e], 1);
    bucket_tok[pos] = p >> 1;
    bucket_w[pos]   = top_w[p];
  }
}

// ---------------------------------------------------------------------------
// Kernel 3: unified up-proj. M=128, N=128 (half of HE via blockIdx.y),
// K=512, BK=32, dbuf + gload_lds. 512 thr, 8 waves (2M x 4N). LDS 48KB.
// Routed tiles -> hrout[slot][256]; shared tiles -> hs[t][2048].
// ---------------------------------------------------------------------------
__global__ __launch_bounds__(512) void k_up(
    const u16* __restrict__ nxb,
    const u16* __restrict__ W1bT, const u16* __restrict__ W3bT,
    const u16* __restrict__ Ws1bT, const u16* __restrict__ Ws3bT,
    const float* __restrict__ b1, const float* __restrict__ b3,
    const float* __restrict__ bs1, const float* __restrict__ bs3,
    const float* __restrict__ b1f, const float* __restrict__ b3f,
    const int* __restrict__ bucket_tok, const float* __restrict__ bucket_w,
    const int* __restrict__ tiles, const int* __restrict__ n_tiles,
    u16* __restrict__ hrout, u16* __restrict__ hs)
{
  if ((int)blockIdx.x >= n_tiles[0]) return;
  const int info = tiles[blockIdx.x];
  const int e  = info >> 17;
  const int b0 = ((info >> 8) & 0x1FF) << 7;
  const int nt = info & 255;
  const bool sh = (e >= NE);
  const int y  = blockIdx.y;            // HE half: h in [y*128, y*128+128)

  __shared__ __align__(16) char Ab[2][8192];    // 128 x 32k bf16
  __shared__ __align__(16) char B1b[2][8192];   // 128 x 32k
  __shared__ __align__(16) char B3b[2][8192];
  __shared__ int   toks[128];
  __shared__ float tw[128];

  const int tid = threadIdx.x, wid = tid >> 6, lane = tid & 63;
  const int l15 = lane & 15, q = lane >> 4;

  if (tid < 128){
    int tk; float w;
    if (!sh){
      if (tid < nt){ tk = bucket_tok[b0+tid]; w = bucket_w[b0+tid]; }
      else         { tk = 0; w = 0.f; }
    } else {
      tk = ((b0 - PADBASE) & (TT-1)) + tid; w = 1.f;
    }
    toks[tid] = tk; tw[tid] = w;
  }
  __syncthreads();

  const u16* w1e = sh ? (Ws1bT + (size_t)(e-NE)*HE*DM) : (W1bT + (size_t)e*HE*DM);
  const u16* w3e = sh ? (Ws3bT + (size_t)(e-NE)*HE*DM) : (W3bT + (size_t)e*HE*DM);

  const int srow = lane >> 2, soff = (lane & 3)*8;
  const u16* asrc = nxb + (size_t)toks[wid*16 + srow]*DM + soff;
  const u16* b1s  = w1e + (size_t)(y*128 + wid*16 + srow)*DM + soff;
  const u16* b3s  = w3e + (size_t)(y*128 + wid*16 + srow)*DM + soff;
  const int loff = wid*1024;

#define UP_STAGE(ph, k0) do{ \
    gl16(asrc + (k0), Ab[ph] + loff); \
    gl16(b1s  + (k0), B1b[ph] + loff); \
    gl16(b3s  + (k0), B3b[ph] + loff); \
  } while(0)

  const int wm = (wid & 1)*64, wn = (wid >> 1)*32;

  const float* ob1 = sh ? (bs1 + (size_t)(e-NE)*HE) : (b1 + (size_t)e*HE);
  const float* ob3 = sh ? (bs3 + (size_t)(e-NE)*HE) : (b3 + (size_t)e*HE);
  f32x4 acc1[4][2], acc3[4][2];
  #pragma unroll
  for (int fn = 0; fn < 2; fn++){
    const int h = y*128 + wn + fn*16 + l15;
    const float v1 = ob1[h] + b1f[(size_t)e*HE + h];   // concat fold layout
    const float v3 = ob3[h] + b3f[(size_t)e*HE + h];
    #pragma unroll
    for (int fm = 0; fm < 4; fm++){
      acc1[fm][fn] = (f32x4){v1,v1,v1,v1};
      acc3[fm][fn] = (f32x4){v3,v3,v3,v3};
    }
  }

  UP_STAGE(0, 0);
  __syncthreads();

  for (int ks = 0; ks < DM/32; ks++){
    const int cur = ks & 1;
    if (ks < DM/32 - 1) UP_STAGE(cur^1, (ks+1)*32);
    const char* A  = Ab[cur];
    const char* B1 = B1b[cur];
    const char* B3 = B3b[cur];
    bf16x8 fa[4];
    #pragma unroll
    for (int fm = 0; fm < 4; fm++) fa[fm] = frd(A, wm + fm*16 + l15, q);
    #pragma unroll
    for (int fn = 0; fn < 2; fn++){
      bf16x8 fb1 = frd(B1, wn + fn*16 + l15, q);
      bf16x8 fb3 = frd(B3, wn + fn*16 + l15, q);
      #pragma unroll
      for (int fm = 0; fm < 4; fm++){
        acc1[fm][fn] = mfma16(fa[fm], fb1, acc1[fm][fn]);
        acc3[fm][fn] = mfma16(fa[fm], fb3, acc3[fm][fn]);
      }
    }
    __syncthreads();
  }
#undef UP_STAGE

  const int tbase = sh ? ((b0 - PADBASE) & (TT-1)) : 0;
  const int scol  = sh ? (e - NE)*HE : 0;
  #pragma unroll
  for (int fm = 0; fm < 4; fm++){
    #pragma unroll
    for (int fn = 0; fn < 2; fn++){
      const int hl = y*128 + wn + fn*16 + l15;
      #pragma unroll
      for (int r = 0; r < 4; r++){
        const int m = wm + fm*16 + 4*q + r;
        float v = 0.f;
        if (m < nt){
          const float a1 = acc1[fm][fn][r];
          const float a3 = acc3[fm][fn][r];
          v = a1 * sig_(a1) * a3 * tw[m];
        }
        if (sh) hs[(size_t)(tbase+m)*HSH + scol + hl] = f2bf(v);
        else    hrout[(size_t)(b0+m)*HE + hl] = f2bf(v);
      }
    }
  }
}

// ---------------------------------------------------------------------------
// Kernel 4a: shared down (dense, writes out exactly once, incl. bs2).
// M=64, N=128, K=2048, BK=32. grid (TT/64, DM/128), 256 thr, 4 waves (2Mx2N).
// LDS 24KB -> ~6 blocks/CU.
// ---------------------------------------------------------------------------
__global__ __launch_bounds__(256) void k_down_shared(
    const u16* __restrict__ hs, const u16* __restrict__ Ws2bT,
    const float* __restrict__ bs2, float* __restrict__ out)
{
  __shared__ __align__(16) char Ab[2][4096];    // 64 x 32k
  __shared__ __align__(16) char Bb[2][8192];    // 128 x 32k

  const int tid = threadIdx.x, wid = tid >> 6, lane = tid & 63;
  const int l15 = lane & 15, q = lane >> 4;
  const int t0 = blockIdx.x*64, d0 = blockIdx.y*128;

  const int srow = tid >> 2, soff = (tid & 3)*8;  // srow 0..63
  const u16* asrc  = hs    + (size_t)(t0 + srow)*HSH + soff;
  const u16* bsrc0 = Ws2bT + (size_t)(d0 + srow)*HSH + soff;
  const u16* bsrc1 = Ws2bT + (size_t)(d0 + 64 + srow)*HSH + soff;
  const int loff = wid*1024;

#define DS_STAGE(ph, k0) do{ \
    gl16(asrc  + (k0), Ab[ph] + loff); \
    gl16(bsrc0 + (k0), Bb[ph] + loff); \
    gl16(bsrc1 + (k0), Bb[ph] + 4096 + loff); \
  } while(0)

  const int wm = (wid & 1)*32, wn = (wid >> 1)*64;

  f32x4 acc[2][4];
  #pragma unroll
  for (int fm = 0; fm < 2; fm++)
    #pragma unroll
    for (int fn = 0; fn < 4; fn++) acc[fm][fn] = (f32x4){0.f,0.f,0.f,0.f};

  DS_STAGE(0, 0);
  __syncthreads();

  for (int ks = 0; ks < HSH/32; ks++){
    const int cur = ks & 1;
    if (ks < HSH/32 - 1) DS_STAGE(cur^1, (ks+1)*32);
    const char* A = Ab[cur];
    const char* B = Bb[cur];
    bf16x8 fa[2];
    #pragma unroll
    for (int fm = 0; fm < 2; fm++) fa[fm] = frd(A, wm + fm*16 + l15, q);
    #pragma unroll
    for (int fn = 0; fn < 4; fn++){
      bf16x8 fb = frd(B, wn + fn*16 + l15, q);
      #pragma unroll
      for (int fm = 0; fm < 2; fm++)
        acc[fm][fn] = mfma16(fa[fm], fb, acc[fm][fn]);
    }
    __syncthreads();
  }
#undef DS_STAGE

  #pragma unroll
  for (int fm = 0; fm < 2; fm++){
    #pragma unroll
    for (int fn = 0; fn < 4; fn++){
      const int d = d0 + wn + fn*16 + l15;
      const float bv = bs2[d];
      #pragma unroll
      for (int r = 0; r < 4; r++){
        const int t = t0 + wm + fm*16 + 4*q + r;
        out[(size_t)t*DM + d] = acc[fm][fn][r] + bv;
      }
    }
  }
}

// ---------------------------------------------------------------------------
// Kernel 4b: routed down. M=128, N=256 (half of DM via blockIdx.y), K=256.
// grid (MAXRT, 2), 512 thr, 8 waves (2M x 4N). LDS 48KB. atomicAdd into out
// (runs AFTER k_down_shared, which wrote the base value).
// ---------------------------------------------------------------------------
__global__ __launch_bounds__(512) void k_down_routed(
    const u16* __restrict__ hrout, const u16* __restrict__ W2bT,
    const float* __restrict__ b2,
    const int* __restrict__ bucket_tok, const float* __restrict__ bucket_w,
    const int* __restrict__ tiles, const int* __restrict__ n_tiles,
    float* __restrict__ out)
{
  if ((int)blockIdx.x >= n_tiles[1]) return;
  const int info = tiles[blockIdx.x];
  const int e  = info >> 17;
  const int b0 = ((info >> 8) & 0x1FF) << 7;
  const int nt = info & 255;
  const int d0 = blockIdx.y * 256;

  __shared__ __align__(16) char Ab[2][8192];     // 128 x 32k
  __shared__ __align__(16) char Bb[2][16384];    // 256 x 32k
  __shared__ int   toks[128];
  __shared__ float tw[128];

  const int tid = threadIdx.x, wid = tid >> 6, lane = tid & 63;
  const int l15 = lane & 15, q = lane >> 4;

  if (tid < 128){
    if (tid < nt){ toks[tid] = bucket_tok[b0+tid]; tw[tid] = bucket_w[b0+tid]; }
    else         { toks[tid] = 0; tw[tid] = 0.f; }
  }
  __syncthreads();

  const u16* w2e = W2bT + (size_t)e*DM*HE;
  const int srow = tid >> 2, soff = (tid & 3)*8;  // srow 0..127
  const u16* asrc  = hrout + (size_t)(b0 + srow)*HE + soff;
  const u16* bsrc0 = w2e + (size_t)(d0 + srow)*HE + soff;
  const u16* bsrc1 = w2e + (size_t)(d0 + 128 + srow)*HE + soff;
  const int loff = wid*1024;

#define DR_STAGE(ph, k0) do{ \
    gl16(asrc  + (k0), Ab[ph] + loff); \
    gl16(bsrc0 + (k0), Bb[ph] + loff); \
    gl16(bsrc1 + (k0), Bb[ph] + 8192 + loff); \
  } while(0)

  const int wm = (wid & 1)*64, wn = (wid >> 1)*64;

  f32x4 acc[4][4];
  #pragma unroll
  for (int fm = 0; fm < 4; fm++)
    #pragma unroll
    for (int fn = 0; fn < 4; fn++) acc[fm][fn] = (f32x4){0.f,0.f,0.f,0.f};

  DR_STAGE(0, 0);
  __syncthreads();

  for (int ks = 0; ks < HE/32; ks++){
    const int cur = ks & 1;
    if (ks < HE/32 - 1) DR_STAGE(cur^1, (ks+1)*32);
    const char* A = Ab[cur];
    const char* B = Bb[cur];
    bf16x8 fa[4];
    #pragma unroll
    for (int fm = 0; fm < 4; fm++) fa[fm] = frd(A, wm + fm*16 + l15, q);
    #pragma unroll
    for (int fn = 0; fn < 4; fn++){
      bf16x8 fb = frd(B, wn + fn*16 + l15, q);
      #pragma unroll
      for (int fm = 0; fm < 4; fm++)
        acc[fm][fn] = mfma16(fa[fm], fb, acc[fm][fn]);
    }
    __syncthreads();
  }
#undef DR_STAGE

  #pragma unroll
  for (int fm = 0; fm < 4; fm++){
    #pragma unroll
    for (int fn = 0; fn < 4; fn++){
      const int d = d0 + wn + fn*16 + l15;
      #pragma unroll
      for (int r = 0; r < 4; r++){
        const int m = wm + fm*16 + 4*q + r;
        if (m < nt)
          atomicAdd(out + (size_t)toks[m]*DM + d, acc[fm][fn][r] + tw[m]*b2[(size_t)e*DM + d]);
      }
    }
  }
}

// ---------------------------------------------------------------------------
extern "C" void kernel_launch(void* const* d_in, const int* in_sizes, int n_in,
                              void* d_out, int out_size, void* d_ws, size_t ws_size,
                              hipStream_t stream)
{
  (void)in_sizes; (void)n_in; (void)ws_size; (void)out_size;
  const float* x     = (const float*)d_in[0];
  const float* Wg    = (const float*)d_in[1];
  const float* bg    = (const float*)d_in[2];
  const float* gamma = (const float*)d_in[3];
  const float* beta  = (const float*)d_in[4];
  const float* W1    = (const float*)d_in[5];
  const float* b1    = (const float*)d_in[6];
  const float* W3    = (const float*)d_in[7];
  const float* b3    = (const float*)d_in[8];
  const float* W2    = (const float*)d_in[9];
  const float* b2    = (const float*)d_in[10];
  const float* gs    = (const float*)d_in[11];
  const float* bs    = (const float*)d_in[12];
  const float* Ws1   = (const float*)d_in[13];
  const float* bs1   = (const float*)d_in[14];
  const float* Ws3   = (const float*)d_in[15];
  const float* bs3   = (const float*)d_in[16];
  const float* Ws2   = (const float*)d_in[17];
  const float* bs2   = (const float*)d_in[18];
  float* out = (float*)d_out;

  char* ws = (char*)d_ws;
  size_t off = 0;
  auto alloc = [&](size_t bytes) -> char* {
    char* p = ws + off;
    off += (bytes + 255) & ~(size_t)255;
    return p;
  };
  u16*   nxb        = (u16*)  alloc((size_t)TT*DM*2);
  int*   top_idx    = (int*)  alloc((size_t)TT*2*4);
  float* top_w      = (float*)alloc((size_t)TT*2*4);
  int*   bucket_tok = (int*)  alloc((size_t)PADBASE*4);
  float* bucket_w   = (float*)alloc((size_t)PADBASE*4);
  int*   tiles      = (int*)  alloc(MAXTILES*4);
  int*   n_tiles    = (int*)  alloc(64);
  u16*   hrout      = (u16*)  alloc((size_t)PADBASE*HE*2);     // 8.4 MB
  u16*   hs         = (u16*)  alloc((size_t)TT*HSH*2);         // 16.8 MB
  u16*   W1bT       = (u16*)  alloc((size_t)NE*HE*DM*2);
  u16*   W3bT       = (u16*)  alloc((size_t)NE*HE*DM*2);
  u16*   W2bT       = (u16*)  alloc((size_t)NE*DM*HE*2);
  u16*   Ws1bT      = (u16*)  alloc((size_t)HSH*DM*2);
  u16*   Ws3bT      = (u16*)  alloc((size_t)HSH*DM*2);
  u16*   Ws2bT      = (u16*)  alloc((size_t)DM*HSH*2);
  float* b1f        = (float*)alloc((size_t)(NE*HE + HSH)*4);  // routed ++ shared folds
  float* b3f        = (float*)alloc((size_t)(NE*HE + HSH)*4);

  // --- pre-pass: convert/transpose weights, fused bias folds ---
  hipMemsetAsync(b1f, 0, (size_t)(NE*HE + HSH)*4, stream);
  hipMemsetAsync(b3f, 0, (size_t)(NE*HE + HSH)*4, stream);
  k_cvtT<<<dim3(DM/64, HE/64, NE), 256, 0, stream>>>(W1, gamma, beta, W1bT, b1f, DM, HE);
  k_cvtT<<<dim3(DM/64, HE/64, NE), 256, 0, stream>>>(W3, gamma, beta, W3bT, b3f, DM, HE);
  k_cvtT<<<dim3(HE/64, DM/64, NE), 256, 0, stream>>>(W2, nullptr, nullptr, W2bT, nullptr, HE, DM);
  k_cvtT<<<dim3(DM/64, HSH/64, 1), 256, 0, stream>>>(Ws1, gs, bs, Ws1bT, b1f + NE*HE, DM, HSH);
  k_cvtT<<<dim3(DM/64, HSH/64, 1), 256, 0, stream>>>(Ws3, gs, bs, Ws3bT, b3f + NE*HE, DM, HSH);
  k_cvtT<<<dim3(HSH/64, DM/64, 1), 256, 0, stream>>>(Ws2, nullptr, nullptr, Ws2bT, nullptr, HSH, DM);

  // --- gate / routing ---
  k_ln_gate<<<dim3(TT), 256, 0, stream>>>(x, Wg, bg, nxb, top_idx, top_w);
  k_route<<<dim3(1), 256, 0, stream>>>(top_idx, top_w, bucket_tok, bucket_w, tiles, n_tiles);

  // --- expert GEMMs ---
  k_up<<<dim3(MAXTILES, 2), 512, 0, stream>>>(nxb, W1bT, W3bT, Ws1bT, Ws3bT,
                                              b1, b3, bs1, bs3, b1f, b3f,
                                              bucket_tok, bucket_w, tiles, n_tiles, hrout, hs);
  k_down_shared<<<dim3(TT/64, DM/128), 256, 0, stream>>>(hs, Ws2bT, bs2, out);
  k_down_routed<<<dim3(MAXRT, 2), 512, 0, stream>>>(hrout, W2bT, b2,
                                                    bucket_tok, bucket_w, tiles, n_tiles, out);
}

// Round 6
// 204.858 us; speedup vs baseline: 13.5178x; 1.1035x over previous
//
#include <hip/hip_runtime.h>
#include <math.h>

typedef unsigned short u16;
typedef __attribute__((ext_vector_type(8))) short bf16x8;
typedef __attribute__((ext_vector_type(4))) float f32x4;

#define TT   4096   // tokens
#define DM   512    // model dim
#define NE   64     // routed experts
#define HE   256    // expert hidden (also pseudo-expert slice of shared)
#define HSH  2048   // shared expert hidden = 8 * 256
#define NSH  8      // shared pseudo-experts
#define PADBASE 16384          // shared tile b0 encoding base
#define MAXTILES 384           // <=128 routed (M=128) + 256 shared
#define MAXRT    128           // max routed tiles

#define WAITV(N) asm volatile("s_waitcnt vmcnt(" #N ")" ::: "memory")
#define SBAR()   __builtin_amdgcn_s_barrier()
#define SCHEDB() __builtin_amdgcn_sched_barrier(0)

__device__ __forceinline__ float sig_(float z){ return 1.f/(1.f+__expf(-z)); }

__device__ __forceinline__ u16 f2bf(float x){
  unsigned int u = __builtin_bit_cast(unsigned int, x);
  u = (u + 0x7FFFu + ((u >> 16) & 1u)) >> 16;
  return (u16)u;
}

__device__ __forceinline__ f32x4 mfma16(bf16x8 a, bf16x8 b, f32x4 c){
  return __builtin_amdgcn_mfma_f32_16x16x32_bf16(a, b, c, 0, 0, 0);
}

// swizzled fragment read: tile row-major [rows][64B]; csw = pre-swizzled chunk byte off
__device__ __forceinline__ bf16x8 frd(const char* tile, int row, int csw){
  return *(const bf16x8*)(tile + row*64 + csw);
}

// async global->LDS, 16B per lane; lds dest = wave-uniform base + lane*16
__device__ __forceinline__ void gl16(const void* g, void* l){
  __builtin_amdgcn_global_load_lds(
      (const __attribute__((address_space(1))) unsigned int*)g,
      (__attribute__((address_space(3))) unsigned int*)l, 16, 0, 0);
}

// ---------------------------------------------------------------------------
// Fused pre-pass: 6 transpose-convert jobs in one launch.
// fp32 [K][N] -> bf16 [N][K], optional row scale (gamma), fused bias fold:
// fout[z*N + n] += sum_k fvec[z*K+k] * W[k][n].
// ---------------------------------------------------------------------------
struct CvtJob {
  const float* in; const float* scale; const float* fvec;
  u16* out; float* fout; int K; int N; int base;
};
struct CvtJobs { CvtJob j[6]; };

__global__ __launch_bounds__(256) void k_cvt_all(CvtJobs jobs)
{
  const int bid = blockIdx.x;
  int ji = 0;
  #pragma unroll
  for (int i = 1; i < 6; i++) ji = (bid >= jobs.j[i].base) ? i : ji;
  const CvtJob J = jobs.j[ji];
  const int local = bid - J.base;
  const int nbx = J.K >> 6, nby = J.N >> 6;
  const int pm = nbx * nby;
  const int z = local / pm, rem = local - z*pm;
  const int bx = rem % nbx, by = rem / nbx;

  __shared__ u16 T[64][80];
  __shared__ float red[64][65];
  const int tid = threadIdx.x;
  const int k0 = bx*64, n0 = by*64;
  const float* ip = J.in + (size_t)z * J.K * J.N;
  const int r = tid>>2, cb = (tid&3)*16;
  const float sc = J.scale ? J.scale[(size_t)z*J.K + k0 + r] : 1.0f;
  const float fv = J.fvec  ? J.fvec [(size_t)z*J.K + k0 + r] : 0.0f;
  #pragma unroll
  for (int jj = 0; jj < 4; jj++){
    float4 v = *(const float4*)(ip + (size_t)(k0+r)*J.N + n0 + cb + jj*4);
    T[cb+jj*4+0][r] = f2bf(v.x*sc);
    T[cb+jj*4+1][r] = f2bf(v.y*sc);
    T[cb+jj*4+2][r] = f2bf(v.z*sc);
    T[cb+jj*4+3][r] = f2bf(v.w*sc);
    if (J.fout){
      red[cb+jj*4+0][r] = v.x*fv;
      red[cb+jj*4+1][r] = v.y*fv;
      red[cb+jj*4+2][r] = v.z*fv;
      red[cb+jj*4+3][r] = v.w*fv;
    }
  }
  __syncthreads();
  if (J.fout){
    const int c = tid & 63, rq = tid >> 6;
    float s = 0.f;
    #pragma unroll
    for (int rr = 0; rr < 16; rr++) s += red[c][rq*16 + rr];
    atomicAdd(J.fout + (size_t)z*J.N + n0 + c, s);
  }
  const int n = tid>>2, kb = (tid&3)*16;
  uint4 a = *(const uint4*)&T[n][kb];
  uint4 b = *(const uint4*)&T[n][kb+8];
  u16* op = J.out + (size_t)z*J.K*J.N;
  *(uint4*)(op + (size_t)(n0+n)*J.K + k0 + kb)     = a;
  *(uint4*)(op + (size_t)(n0+n)*J.K + k0 + kb + 8) = b;
}

// ---------------------------------------------------------------------------
// Kernel 1: per-token LN stats -> nxb (bf16), gate logits + top-2.
// ---------------------------------------------------------------------------
__global__ __launch_bounds__(256) void k_ln_gate(
    const float* __restrict__ x, const float* __restrict__ Wg, const float* __restrict__ bg,
    u16* __restrict__ nxb, int* __restrict__ top_idx, float* __restrict__ top_w)
{
  __shared__ float xs[DM];
  __shared__ float sred[4], ssred[4];
  __shared__ float sc[NE];
  const int tid = threadIdx.x;
  const int t   = blockIdx.x;

  float2 v = reinterpret_cast<const float2*>(x + (size_t)t*DM)[tid];
  xs[2*tid]   = v.x;
  xs[2*tid+1] = v.y;
  float s  = v.x + v.y;
  float ss = v.x*v.x + v.y*v.y;
  #pragma unroll
  for (int o = 32; o > 0; o >>= 1){ s += __shfl_xor(s, o); ss += __shfl_xor(ss, o); }
  const int wid = tid >> 6, lane = tid & 63;
  if (lane == 0){ sred[wid] = s; ssred[wid] = ss; }
  __syncthreads();
  const float tot = sred[0]+sred[1]+sred[2]+sred[3];
  const float tss = ssred[0]+ssred[1]+ssred[2]+ssred[3];
  const float mu  = tot * (1.f/DM);
  const float var = tss * (1.f/DM) - mu*mu;
  const float rstd = rsqrtf(var + 1e-5f);
  unsigned int pk = (unsigned int)f2bf((v.x-mu)*rstd) | ((unsigned int)f2bf((v.y-mu)*rstd) << 16);
  *(unsigned int*)(nxb + (size_t)t*DM + 2*tid) = pk;

  const int e = tid >> 2, sub = tid & 3;
  const float4* wrow4 = reinterpret_cast<const float4*>(Wg + (size_t)e*DM);
  const float4* xs4   = reinterpret_cast<const float4*>(xs);
  float acc = 0.f;
  #pragma unroll 4
  for (int i = sub; i < DM/4; i += 4){
    const float4 w = wrow4[i]; const float4 xv = xs4[i];
    acc += xv.x*w.x + xv.y*w.y + xv.z*w.z + xv.w*w.w;
  }
  acc += __shfl_xor(acc, 1);
  acc += __shfl_xor(acc, 2);
  if (sub == 0) sc[e] = acc + bg[e];
  __syncthreads();

  if (tid < 64) {
    const float s0 = sc[tid];
    float m = s0; int mi = tid;
    #pragma unroll
    for (int o = 1; o < 64; o <<= 1){
      float om = __shfl_xor(m, o); int oi = __shfl_xor(mi, o);
      if (om > m || (om == m && oi < mi)) { m = om; mi = oi; }
    }
    float s1 = (tid == mi) ? -INFINITY : s0;
    float m2 = s1; int mi2 = tid;
    #pragma unroll
    for (int o = 1; o < 64; o <<= 1){
      float om = __shfl_xor(m2, o); int oi = __shfl_xor(mi2, o);
      if (om > m2 || (om == m2 && oi < mi2)) { m2 = om; mi2 = oi; }
    }
    if (tid == 0){
      const float w0 = sig_(m), w1 = sig_(m2);
      const float inv = 1.f/(w0+w1);
      top_idx[2*t]   = mi;
      top_idx[2*t+1] = mi2;
      top_w[2*t]     = w0*inv;
      top_w[2*t+1]   = w1*inv;
    }
  }
}

// ---------------------------------------------------------------------------
// Kernel 2: routing. Padded (M=128) per-expert bases, scatter, tile list.
// ---------------------------------------------------------------------------
__global__ __launch_bounds__(256) void k_route(
    const int* __restrict__ top_idx, const float* __restrict__ top_w,
    int* __restrict__ bucket_tok, float* __restrict__ bucket_w,
    int* __restrict__ tiles, int* __restrict__ n_tiles)
{
  __shared__ int cnt[NE], base_[NE];
  __shared__ int nroute;
  const int tid = threadIdx.x;
  if (tid < NE) cnt[tid] = 0;
  __syncthreads();
  for (int p = tid; p < TT*2; p += 256) atomicAdd(&cnt[top_idx[p]], 1);
  __syncthreads();
  if (tid == 0){
    int run = 0, ntl = 0;
    for (int e = 0; e < NE; e++){
      base_[e] = run;
      const int c = cnt[e];
      for (int b = 0; b < c; b += 128){
        const int n = (c - b < 128) ? (c - b) : 128;
        tiles[ntl++] = (e << 17) | (((run + b) >> 7) << 8) | n;
      }
      run += ((c + 127) >> 7) << 7;   // padded advance
    }
    nroute = ntl;
    n_tiles[0] = ntl + NSH*(TT/128);
    n_tiles[1] = ntl;
  }
  __syncthreads();
  if (tid < NSH*(TT/128)){
    const int s = tid >> 5, t = tid & 31;     // TT/128 = 32
    const int b0 = PADBASE + s*TT + t*128;
    tiles[nroute + tid] = ((NE + s) << 17) | ((b0 >> 7) << 8) | 128;
  }
  if (tid < NE) cnt[tid] = 0;
  __syncthreads();
  for (int p = tid; p < TT*2; p += 256){
    const int e = top_idx[p];
    const int pos = base_[e] + atomicAdd(&cnt[e], 1);
    bucket_tok[pos] = p >> 1;
    bucket_w[pos]   = top_w[p];
  }
}

// ---------------------------------------------------------------------------
// Kernel 3: unified up-proj. M=128, N=128 (HE half via blockIdx.y), K=512,
// BK=32. 3-buffer counted-vmcnt pipeline + LDS XOR swizzle. 512 thr, 8 waves.
// ---------------------------------------------------------------------------
__global__ __launch_bounds__(512) void k_up(
    const u16* __restrict__ nxb,
    const u16* __restrict__ W1bT, const u16* __restrict__ W3bT,
    const u16* __restrict__ Ws1bT, const u16* __restrict__ Ws3bT,
    const float* __restrict__ b1, const float* __restrict__ b3,
    const float* __restrict__ bs1, const float* __restrict__ bs3,
    const float* __restrict__ b1f, const float* __restrict__ b3f,
    const int* __restrict__ bucket_tok, const float* __restrict__ bucket_w,
    const int* __restrict__ tiles, const int* __restrict__ n_tiles,
    u16* __restrict__ hrout, u16* __restrict__ hs)
{
  if ((int)blockIdx.x >= n_tiles[0]) return;
  const int info = tiles[blockIdx.x];
  const int e  = info >> 17;
  const int b0 = ((info >> 8) & 0x1FF) << 7;
  const int nt = info & 255;
  const bool sh = (e >= NE);
  const int y  = blockIdx.y;            // HE half

  __shared__ __align__(16) char Ab[3][8192];
  __shared__ __align__(16) char B1b[3][8192];
  __shared__ __align__(16) char B3b[3][8192];
  __shared__ int   toks[128];
  __shared__ float tw[128];

  const int tid = threadIdx.x, wid = tid >> 6, lane = tid & 63;
  const int l15 = lane & 15, q = lane >> 4;

  if (tid < 128){
    int tk; float w;
    if (!sh){
      if (tid < nt){ tk = bucket_tok[b0+tid]; w = bucket_w[b0+tid]; }
      else         { tk = 0; w = 0.f; }
    } else {
      tk = ((b0 - PADBASE) & (TT-1)) + tid; w = 1.f;
    }
    toks[tid] = tk; tw[tid] = w;
  }
  __syncthreads();

  const u16* w1e = sh ? (Ws1bT + (size_t)(e-NE)*HE*DM) : (W1bT + (size_t)e*HE*DM);
  const u16* w3e = sh ? (Ws3bT + (size_t)(e-NE)*HE*DM) : (W3bT + (size_t)e*HE*DM);

  // stage: srow = lane>>2, chunk c = lane&3, source chunk pre-swizzled c^((srow>>1)&3)
  const int srow = lane >> 2;
  const int csrc = (((lane & 3) ^ ((lane >> 3) & 3))) * 8;
  const u16* asrc = nxb + (size_t)toks[wid*16 + srow]*DM + csrc;
  const u16* b1s  = w1e + (size_t)(y*128 + wid*16 + srow)*DM + csrc;
  const u16* b3s  = w3e + (size_t)(y*128 + wid*16 + srow)*DM + csrc;
  const int loff = wid*1024;

#define UP_STAGE(ph, k0) do{ \
    gl16(asrc + (k0), Ab[ph] + loff); \
    gl16(b1s  + (k0), B1b[ph] + loff); \
    gl16(b3s  + (k0), B3b[ph] + loff); \
  } while(0)

  const int wm = (wid & 1)*64, wn = (wid >> 1)*32;

  const float* ob1 = sh ? (bs1 + (size_t)(e-NE)*HE) : (b1 + (size_t)e*HE);
  const float* ob3 = sh ? (bs3 + (size_t)(e-NE)*HE) : (b3 + (size_t)e*HE);
  f32x4 acc1[4][2], acc3[4][2];
  #pragma unroll
  for (int fn = 0; fn < 2; fn++){
    const int h = y*128 + wn + fn*16 + l15;
    const float v1 = ob1[h] + b1f[(size_t)e*HE + h];
    const float v3 = ob3[h] + b3f[(size_t)e*HE + h];
    #pragma unroll
    for (int fm = 0; fm < 4; fm++){
      acc1[fm][fn] = (f32x4){v1,v1,v1,v1};
      acc3[fm][fn] = (f32x4){v3,v3,v3,v3};
    }
  }

  UP_STAGE(0, 0);
  UP_STAGE(1, 32);
  const int csw = (q ^ ((l15 >> 1) & 3)) * 16;   // swizzled read chunk

  for (int ks = 0; ks < DM/32; ks++){
    const int cur = ks % 3;
    if (ks + 2 < DM/32) UP_STAGE((ks+2)%3, (ks+2)*32);
    if (ks < DM/32 - 2)       WAITV(6);
    else if (ks == DM/32 - 2) WAITV(3);
    else                      WAITV(0);
    SBAR();
    __builtin_amdgcn_s_setprio(1);
    const char* A  = Ab[cur];
    const char* B1 = B1b[cur];
    const char* B3 = B3b[cur];
    bf16x8 fa[4];
    #pragma unroll
    for (int fm = 0; fm < 4; fm++) fa[fm] = frd(A, wm + fm*16 + l15, csw);
    #pragma unroll
    for (int fn = 0; fn < 2; fn++){
      bf16x8 fb1 = frd(B1, wn + fn*16 + l15, csw);
      bf16x8 fb3 = frd(B3, wn + fn*16 + l15, csw);
      #pragma unroll
      for (int fm = 0; fm < 4; fm++){
        acc1[fm][fn] = mfma16(fa[fm], fb1, acc1[fm][fn]);
        acc3[fm][fn] = mfma16(fa[fm], fb3, acc3[fm][fn]);
      }
    }
    __builtin_amdgcn_s_setprio(0);
    SCHEDB();
    SBAR();
  }
#undef UP_STAGE

  const int tbase = sh ? ((b0 - PADBASE) & (TT-1)) : 0;
  const int scol  = sh ? (e - NE)*HE : 0;
  #pragma unroll
  for (int fm = 0; fm < 4; fm++){
    #pragma unroll
    for (int fn = 0; fn < 2; fn++){
      const int hl = y*128 + wn + fn*16 + l15;
      #pragma unroll
      for (int r = 0; r < 4; r++){
        const int m = wm + fm*16 + 4*q + r;
        float v = 0.f;
        if (m < nt){
          const float a1 = acc1[fm][fn][r];
          const float a3 = acc3[fm][fn][r];
          v = a1 * sig_(a1) * a3 * tw[m];
        }
        if (sh) hs[(size_t)(tbase+m)*HSH + scol + hl] = f2bf(v);
        else    hrout[(size_t)(b0+m)*HE + hl] = f2bf(v);
      }
    }
  }
}

// ---------------------------------------------------------------------------
// Kernel 4a: shared down (dense, writes out once, incl. bs2). M=64, N=128,
// K=2048, BK=32, 3-buffer pipeline + swizzle. 256 thr, 4 waves (2Mx2N).
// ---------------------------------------------------------------------------
__global__ __launch_bounds__(256) void k_down_shared(
    const u16* __restrict__ hs, const u16* __restrict__ Ws2bT,
    const float* __restrict__ bs2, float* __restrict__ out)
{
  __shared__ __align__(16) char Ab[3][4096];
  __shared__ __align__(16) char Bb[3][8192];

  const int tid = threadIdx.x, wid = tid >> 6, lane = tid & 63;
  const int l15 = lane & 15, q = lane >> 4;
  const int t0 = blockIdx.x*64, d0 = blockIdx.y*128;

  const int srow = tid >> 2;
  const int csrc = (((tid & 3) ^ ((tid >> 3) & 3))) * 8;
  const u16* asrc  = hs    + (size_t)(t0 + srow)*HSH + csrc;
  const u16* bsrc0 = Ws2bT + (size_t)(d0 + srow)*HSH + csrc;
  const u16* bsrc1 = Ws2bT + (size_t)(d0 + 64 + srow)*HSH + csrc;
  const int loff = wid*1024;

#define DS_STAGE(ph, k0) do{ \
    gl16(asrc  + (k0), Ab[ph] + loff); \
    gl16(bsrc0 + (k0), Bb[ph] + loff); \
    gl16(bsrc1 + (k0), Bb[ph] + 4096 + loff); \
  } while(0)

  const int wm = (wid & 1)*32, wn = (wid >> 1)*64;

  f32x4 acc[2][4];
  #pragma unroll
  for (int fm = 0; fm < 2; fm++)
    #pragma unroll
    for (int fn = 0; fn < 4; fn++) acc[fm][fn] = (f32x4){0.f,0.f,0.f,0.f};

  DS_STAGE(0, 0);
  DS_STAGE(1, 32);
  const int csw = (q ^ ((l15 >> 1) & 3)) * 16;

  for (int ks = 0; ks < HSH/32; ks++){
    const int cur = ks % 3;
    if (ks + 2 < HSH/32) DS_STAGE((ks+2)%3, (ks+2)*32);
    if (ks < HSH/32 - 2)       WAITV(6);
    else if (ks == HSH/32 - 2) WAITV(3);
    else                       WAITV(0);
    SBAR();
    __builtin_amdgcn_s_setprio(1);
    const char* A = Ab[cur];
    const char* B = Bb[cur];
    bf16x8 fa[2];
    #pragma unroll
    for (int fm = 0; fm < 2; fm++) fa[fm] = frd(A, wm + fm*16 + l15, csw);
    #pragma unroll
    for (int fn = 0; fn < 4; fn++){
      bf16x8 fb = frd(B, wn + fn*16 + l15, csw);
      #pragma unroll
      for (int fm = 0; fm < 2; fm++)
        acc[fm][fn] = mfma16(fa[fm], fb, acc[fm][fn]);
    }
    __builtin_amdgcn_s_setprio(0);
    SCHEDB();
    SBAR();
  }
#undef DS_STAGE

  #pragma unroll
  for (int fm = 0; fm < 2; fm++){
    #pragma unroll
    for (int fn = 0; fn < 4; fn++){
      const int d = d0 + wn + fn*16 + l15;
      const float bv = bs2[d];
      #pragma unroll
      for (int r = 0; r < 4; r++){
        const int t = t0 + wm + fm*16 + 4*q + r;
        out[(size_t)t*DM + d] = acc[fm][fn][r] + bv;
      }
    }
  }
}

// ---------------------------------------------------------------------------
// Kernel 4b: routed down. M=128, N=256 (DM half via blockIdx.y), K=256,
// BK=32, 3-buffer pipeline + swizzle. 512 thr. atomicAdd into out.
// ---------------------------------------------------------------------------
__global__ __launch_bounds__(512) void k_down_routed(
    const u16* __restrict__ hrout, const u16* __restrict__ W2bT,
    const float* __restrict__ b2,
    const int* __restrict__ bucket_tok, const float* __restrict__ bucket_w,
    const int* __restrict__ tiles, const int* __restrict__ n_tiles,
    float* __restrict__ out)
{
  if ((int)blockIdx.x >= n_tiles[1]) return;
  const int info = tiles[blockIdx.x];
  const int e  = info >> 17;
  const int b0 = ((info >> 8) & 0x1FF) << 7;
  const int nt = info & 255;
  const int d0 = blockIdx.y * 256;

  __shared__ __align__(16) char Ab[3][8192];
  __shared__ __align__(16) char Bb[3][16384];
  __shared__ int   toks[128];
  __shared__ float tw[128];

  const int tid = threadIdx.x, wid = tid >> 6, lane = tid & 63;
  const int l15 = lane & 15, q = lane >> 4;

  if (tid < 128){
    if (tid < nt){ toks[tid] = bucket_tok[b0+tid]; tw[tid] = bucket_w[b0+tid]; }
    else         { toks[tid] = 0; tw[tid] = 0.f; }
  }
  __syncthreads();

  const u16* w2e = W2bT + (size_t)e*DM*HE;
  const int srow = tid >> 2;
  const int csrc = (((tid & 3) ^ ((tid >> 3) & 3))) * 8;
  const u16* asrc  = hrout + (size_t)(b0 + srow)*HE + csrc;
  const u16* bsrc0 = w2e + (size_t)(d0 + srow)*HE + csrc;
  const u16* bsrc1 = w2e + (size_t)(d0 + 128 + srow)*HE + csrc;
  const int loff = wid*1024;

#define DR_STAGE(ph, k0) do{ \
    gl16(asrc  + (k0), Ab[ph] + loff); \
    gl16(bsrc0 + (k0), Bb[ph] + loff); \
    gl16(bsrc1 + (k0), Bb[ph] + 8192 + loff); \
  } while(0)

  const int wm = (wid & 1)*64, wn = (wid >> 1)*64;

  f32x4 acc[4][4];
  #pragma unroll
  for (int fm = 0; fm < 4; fm++)
    #pragma unroll
    for (int fn = 0; fn < 4; fn++) acc[fm][fn] = (f32x4){0.f,0.f,0.f,0.f};

  DR_STAGE(0, 0);
  DR_STAGE(1, 32);
  const int csw = (q ^ ((l15 >> 1) & 3)) * 16;

  for (int ks = 0; ks < HE/32; ks++){
    const int cur = ks % 3;
    if (ks + 2 < HE/32) DR_STAGE((ks+2)%3, (ks+2)*32);
    if (ks < HE/32 - 2)       WAITV(6);
    else if (ks == HE/32 - 2) WAITV(3);
    else                      WAITV(0);
    SBAR();
    __builtin_amdgcn_s_setprio(1);
    const char* A = Ab[cur];
    const char* B = Bb[cur];
    bf16x8 fa[4];
    #pragma unroll
    for (int fm = 0; fm < 4; fm++) fa[fm] = frd(A, wm + fm*16 + l15, csw);
    #pragma unroll
    for (int fn = 0; fn < 4; fn++){
      bf16x8 fb = frd(B, wn + fn*16 + l15, csw);
      #pragma unroll
      for (int fm = 0; fm < 4; fm++)
        acc[fm][fn] = mfma16(fa[fm], fb, acc[fm][fn]);
    }
    __builtin_amdgcn_s_setprio(0);
    SCHEDB();
    SBAR();
  }
#undef DR_STAGE

  #pragma unroll
  for (int fm = 0; fm < 4; fm++){
    #pragma unroll
    for (int fn = 0; fn < 4; fn++){
      const int d = d0 + wn + fn*16 + l15;
      #pragma unroll
      for (int r = 0; r < 4; r++){
        const int m = wm + fm*16 + 4*q + r;
        if (m < nt)
          atomicAdd(out + (size_t)toks[m]*DM + d, acc[fm][fn][r] + tw[m]*b2[(size_t)e*DM + d]);
      }
    }
  }
}

// ---------------------------------------------------------------------------
extern "C" void kernel_launch(void* const* d_in, const int* in_sizes, int n_in,
                              void* d_out, int out_size, void* d_ws, size_t ws_size,
                              hipStream_t stream)
{
  (void)in_sizes; (void)n_in; (void)ws_size; (void)out_size;
  const float* x     = (const float*)d_in[0];
  const float* Wg    = (const float*)d_in[1];
  const float* bg    = (const float*)d_in[2];
  const float* gamma = (const float*)d_in[3];
  const float* beta  = (const float*)d_in[4];
  const float* W1    = (const float*)d_in[5];
  const float* b1    = (const float*)d_in[6];
  const float* W3    = (const float*)d_in[7];
  const float* b3    = (const float*)d_in[8];
  const float* W2    = (const float*)d_in[9];
  const float* b2    = (const float*)d_in[10];
  const float* gs    = (const float*)d_in[11];
  const float* bs    = (const float*)d_in[12];
  const float* Ws1   = (const float*)d_in[13];
  const float* bs1   = (const float*)d_in[14];
  const float* Ws3   = (const float*)d_in[15];
  const float* bs3   = (const float*)d_in[16];
  const float* Ws2   = (const float*)d_in[17];
  const float* bs2   = (const float*)d_in[18];
  float* out = (float*)d_out;

  char* ws = (char*)d_ws;
  size_t off = 0;
  auto alloc = [&](size_t bytes) -> char* {
    char* p = ws + off;
    off += (bytes + 255) & ~(size_t)255;
    return p;
  };
  u16*   nxb        = (u16*)  alloc((size_t)TT*DM*2);
  int*   top_idx    = (int*)  alloc((size_t)TT*2*4);
  float* top_w      = (float*)alloc((size_t)TT*2*4);
  int*   bucket_tok = (int*)  alloc((size_t)PADBASE*4);
  float* bucket_w   = (float*)alloc((size_t)PADBASE*4);
  int*   tiles      = (int*)  alloc(MAXTILES*4);
  int*   n_tiles    = (int*)  alloc(64);
  u16*   hrout      = (u16*)  alloc((size_t)PADBASE*HE*2);
  u16*   hs         = (u16*)  alloc((size_t)TT*HSH*2);
  u16*   W1bT       = (u16*)  alloc((size_t)NE*HE*DM*2);
  u16*   W3bT       = (u16*)  alloc((size_t)NE*HE*DM*2);
  u16*   W2bT       = (u16*)  alloc((size_t)NE*DM*HE*2);
  u16*   Ws1bT      = (u16*)  alloc((size_t)HSH*DM*2);
  u16*   Ws3bT      = (u16*)  alloc((size_t)HSH*DM*2);
  u16*   Ws2bT      = (u16*)  alloc((size_t)DM*HSH*2);
  float* b1f        = (float*)alloc((size_t)(NE*HE + HSH)*4);
  float* b3f        = (float*)alloc((size_t)(NE*HE + HSH)*4);

  // --- pre-pass: fused convert/transpose + bias folds (one launch) ---
  hipMemsetAsync(b1f, 0, (size_t)(NE*HE + HSH)*4, stream);
  hipMemsetAsync(b3f, 0, (size_t)(NE*HE + HSH)*4, stream);
  CvtJobs jobs;
  // W1 [64][512][256]: 8*4*64 = 2048 blocks
  jobs.j[0] = { W1,  gamma, beta, W1bT,  b1f,          DM,  HE,  0    };
  jobs.j[1] = { W3,  gamma, beta, W3bT,  b3f,          DM,  HE,  2048 };
  jobs.j[2] = { W2,  nullptr, nullptr, W2bT, nullptr,  HE,  DM,  4096 };
  jobs.j[3] = { Ws1, gs, bs, Ws1bT, b1f + NE*HE,       DM,  HSH, 6144 };
  jobs.j[4] = { Ws3, gs, bs, Ws3bT, b3f + NE*HE,       DM,  HSH, 6400 };
  jobs.j[5] = { Ws2, nullptr, nullptr, Ws2bT, nullptr, HSH, DM,  6656 };
  k_cvt_all<<<dim3(6912), 256, 0, stream>>>(jobs);

  // --- gate / routing ---
  k_ln_gate<<<dim3(TT), 256, 0, stream>>>(x, Wg, bg, nxb, top_idx, top_w);
  k_route<<<dim3(1), 256, 0, stream>>>(top_idx, top_w, bucket_tok, bucket_w, tiles, n_tiles);

  // --- expert GEMMs ---
  k_up<<<dim3(MAXTILES, 2), 512, 0, stream>>>(nxb, W1bT, W3bT, Ws1bT, Ws3bT,
                                              b1, b3, bs1, bs3, b1f, b3f,
                                              bucket_tok, bucket_w, tiles, n_tiles, hrout, hs);
  k_down_shared<<<dim3(TT/64, DM/128), 256, 0, stream>>>(hs, Ws2bT, bs2, out);
  k_down_routed<<<dim3(MAXRT, 2), 512, 0, stream>>>(hrout, W2bT, b2,
                                                    bucket_tok, bucket_w, tiles, n_tiles, out);
}